// Round 3
// baseline (455.564 us; speedup 1.0000x reference)
//
#include <hip/hip_runtime.h>
#include <hip/hip_bf16.h>

#define HW_IMG 262144   // 512*512
#define KSEL   26214    // HW_IMG/10
#define NB     8
#define CF     256
#define LDW1   288      // layer-1 K padded (257 -> 288, mult of 32)
#define LDACT  296      // LDS activation row stride (elements)
#define NBLK_MAIN 410   // blocks per batch in k_main

// column swizzle for act: XOR element-index bits 4-5 with bits 6-7.
// Verified per-quarter-wave: gather ds_write_b128 4-way -> 2-way (free),
// MFMA B-reads stay 2-way, epilogue 2-way. Bijective on [0,256), identity on [256,288).
#define ACOL(c) ((c) ^ ((((c) >> 6) & 3) << 4))

typedef short    short8 __attribute__((ext_vector_type(8)));
typedef float    f32x4  __attribute__((ext_vector_type(4)));
typedef unsigned u32x2  __attribute__((ext_vector_type(2)));
typedef unsigned short u16x4 __attribute__((ext_vector_type(4)));

__device__ __forceinline__ unsigned f2key(float f){
    unsigned u = __builtin_bit_cast(unsigned, f);
    return (u & 0x80000000u) ? ~u : (u | 0x80000000u);
}
__device__ __forceinline__ unsigned short f2bf(float f){
    unsigned u = __builtin_bit_cast(unsigned, f);
    u = u + 0x7FFFu + ((u >> 16) & 1u);
    return (unsigned short)(u >> 16);
}
__device__ __forceinline__ float bf2f(unsigned short s){
    unsigned u = ((unsigned)s) << 16;
    return __builtin_bit_cast(float, u);
}

// ---------------- weight prep: fold BN, convert to bf16 ----------------
__global__ __launch_bounds__(256) void k_prep(
    const float* __restrict__ w1, const float* __restrict__ w2,
    const float* __restrict__ b1, const float* __restrict__ g1, const float* __restrict__ be1,
    const float* __restrict__ m1, const float* __restrict__ v1,
    const float* __restrict__ b2, const float* __restrict__ g2, const float* __restrict__ be2,
    const float* __restrict__ m2, const float* __restrict__ v2,
    unsigned short* __restrict__ w1p, unsigned short* __restrict__ w2p,
    float* __restrict__ c1, float* __restrict__ c2)
{
    int tid = blockIdx.x * 256 + threadIdx.x;
    if (tid < 256 * LDW1) {
        int o = tid / LDW1, k = tid % LDW1;
        float scale = g1[o] * rsqrtf(v1[o] + 1e-5f);
        float val = 0.f;
        if (k < 256) val = w1[o * 257 + k + 1];   // fine channel k <- w1 col k+1
        else if (k == 256) val = w1[o * 257];     // coarse <- w1 col 0
        w1p[tid] = f2bf(val * scale);
        if (k == 0) c1[o] = (b1[o] - m1[o]) * scale + be1[o];
    } else {
        int t2 = tid - 256 * LDW1;
        if (t2 < 65536) {
            int o = t2 >> 8;
            float scale = g2[o] * rsqrtf(v2[o] + 1e-5f);
            w2p[t2] = f2bf(w2[t2] * scale);
            if ((t2 & 255) == 0) c2[o] = (b2[o] - m2[o]) * scale + be2[o];
        }
    }
}

// ---------------- enc_f transpose: [B,C,128,128] f32 -> [B,pix,C] bf16 ----------------
__global__ __launch_bounds__(256) void k_transpose(
    const float* __restrict__ enc, unsigned short* __restrict__ encT)
{
    __shared__ __align__(16) unsigned short tile[64][72];
    int b = blockIdx.z;
    int pixbase = blockIdx.x * 64;
    int chbase  = blockIdx.y * 64;
    int t = threadIdx.x;
    int pix = t & 63, cg = t >> 6;
    const float* src = enc + (size_t)b * CF * 16384;
#pragma unroll
    for (int i = 0; i < 16; i++) {
        int c = chbase + cg * 16 + i;
        tile[pix][cg * 16 + i] = f2bf(src[(size_t)c * 16384 + pixbase + pix]);
    }
    __syncthreads();
    unsigned short* dst = encT + (size_t)b * 16384 * CF;
#pragma unroll
    for (int pass = 0; pass < 4; pass++) {
        int pl = pass * 16 + (t >> 4);
        int c4 = (t & 15) * 4;
        *(u16x4*)(dst + (size_t)(pixbase + pl) * CF + chbase + c4) = *(const u16x4*)&tile[pl][c4];
    }
}

// ---------------- selection: 12/12/8-bit radix select ----------------
// meta per batch: [0]=binA [1]=baseA [2]=binB [3]=baseB [4]=binC [5]=cless [6]=pivot

__device__ __forceinline__ void find_stage(const unsigned* __restrict__ h,
    unsigned* __restrict__ meta, int b, int per, int stage, int t)
{
    __shared__ unsigned seg[256], pref[256];
    unsigned s = 0;
    for (int i = 0; i < per; i++) s += h[t * per + i];
    seg[t] = s;
    __syncthreads();
    if (t == 0) {
        unsigned c = (stage == 0) ? 0u : meta[b * 8 + 2 * stage - 1];
        for (int i = 0; i < 256; i++) { pref[i] = c; c += seg[i]; }
    }
    __syncthreads();
    if (pref[t] < KSEL && KSEL <= pref[t] + seg[t]) {
        unsigned c = pref[t];
        for (int i = 0; i < per; i++) {
            unsigned cnt = h[t * per + i];
            if (c + cnt >= KSEL) {
                unsigned bin = (unsigned)(t * per + i);
                meta[b * 8 + 2 * stage] = bin;
                meta[b * 8 + 2 * stage + 1] = c;
                if (stage == 2)
                    meta[b * 8 + 6] = (meta[b * 8 + 0] << 20) | (meta[b * 8 + 2] << 8) | bin;
                break;
            }
            c += cnt;
        }
    }
}

// last-block-per-batch ticket; returns true if this block should run the find
__device__ __forceinline__ bool last_block(unsigned* done, int b, int nblk, int t)
{
    __shared__ unsigned sT;
    __threadfence();
    __syncthreads();
    if (t == 0) sT = atomicAdd(&done[b], 1u);
    __syncthreads();
    if (sT == (unsigned)(nblk - 1)) { __threadfence(); return true; }
    return false;
}

__global__ __launch_bounds__(256) void k_histA(const float* __restrict__ unc,
    unsigned* __restrict__ hist, unsigned* __restrict__ meta, unsigned* __restrict__ done)
{
    __shared__ unsigned lh[4][4096];   // per-wave private copies (64 KB)
    int b = blockIdx.y, t = threadIdx.x;
    int wv = t >> 6;
    for (int i = t; i < 4 * 4096; i += 256) ((unsigned*)lh)[i] = 0;
    __syncthreads();
    const float4* src = (const float4*)(unc + (size_t)b * HW_IMG + blockIdx.x * 4096);
    unsigned* mine = lh[wv];
#pragma unroll
    for (int j = 0; j < 4; j++) {
        float4 v = src[j * 256 + t];
        atomicAdd(&mine[f2key(v.x) >> 20], 1u);
        atomicAdd(&mine[f2key(v.y) >> 20], 1u);
        atomicAdd(&mine[f2key(v.z) >> 20], 1u);
        atomicAdd(&mine[f2key(v.w) >> 20], 1u);
    }
    __syncthreads();
    unsigned* gh = hist + (size_t)b * 4096;
    for (int i = t; i < 4096; i += 256) {
        unsigned c = lh[0][i] + lh[1][i] + lh[2][i] + lh[3][i];
        if (c) atomicAdd(&gh[i], c);
    }
    if (last_block(done, b, gridDim.x, t)) find_stage(gh, meta, b, 16, 0, t);
}

__global__ __launch_bounds__(256) void k_histB(const float* __restrict__ unc,
    const unsigned* __restrict__ metaIn, unsigned* __restrict__ hist,
    unsigned* __restrict__ meta, unsigned* __restrict__ done)
{
    __shared__ unsigned lh[4096];
    int b = blockIdx.y, t = threadIdx.x;
    unsigned binA = metaIn[b * 8 + 0];
    for (int i = t; i < 4096; i += 256) lh[i] = 0;
    __syncthreads();
    const float4* src = (const float4*)(unc + (size_t)b * HW_IMG + blockIdx.x * 4096);
#pragma unroll
    for (int j = 0; j < 4; j++) {
        float4 v = src[j * 256 + t];
        unsigned k;
        k = f2key(v.x); if ((k >> 20) == binA) atomicAdd(&lh[(k >> 8) & 0xFFFu], 1u);
        k = f2key(v.y); if ((k >> 20) == binA) atomicAdd(&lh[(k >> 8) & 0xFFFu], 1u);
        k = f2key(v.z); if ((k >> 20) == binA) atomicAdd(&lh[(k >> 8) & 0xFFFu], 1u);
        k = f2key(v.w); if ((k >> 20) == binA) atomicAdd(&lh[(k >> 8) & 0xFFFu], 1u);
    }
    __syncthreads();
    unsigned* gh = hist + (size_t)b * 4096;
    for (int i = t; i < 4096; i += 256) { unsigned c = lh[i]; if (c) atomicAdd(&gh[i], c); }
    if (last_block(done, b, gridDim.x, t)) find_stage(gh, meta, b, 16, 1, t);
}

__global__ __launch_bounds__(256) void k_histC(const float* __restrict__ unc,
    const unsigned* __restrict__ metaIn, unsigned* __restrict__ hist,
    unsigned* __restrict__ meta, unsigned* __restrict__ done)
{
    __shared__ unsigned lh[256];
    int b = blockIdx.y, t = threadIdx.x;
    unsigned pre24 = (metaIn[b * 8 + 0] << 12) | metaIn[b * 8 + 2];
    lh[t] = 0;
    __syncthreads();
    const float4* src = (const float4*)(unc + (size_t)b * HW_IMG + blockIdx.x * 4096);
#pragma unroll
    for (int j = 0; j < 4; j++) {
        float4 v = src[j * 256 + t];
        unsigned k;
        k = f2key(v.x); if ((k >> 8) == pre24) atomicAdd(&lh[k & 0xFFu], 1u);
        k = f2key(v.y); if ((k >> 8) == pre24) atomicAdd(&lh[k & 0xFFu], 1u);
        k = f2key(v.z); if ((k >> 8) == pre24) atomicAdd(&lh[k & 0xFFu], 1u);
        k = f2key(v.w); if ((k >> 8) == pre24) atomicAdd(&lh[k & 0xFFu], 1u);
    }
    __syncthreads();
    unsigned* gh = hist + (size_t)b * 4096;
    unsigned c = lh[t];
    if (c) atomicAdd(&gh[t], c);
    if (last_block(done, b, gridDim.x, t)) find_stage(gh, meta, b, 1, 2, t);
}

__global__ __launch_bounds__(256) void k_count(const float* __restrict__ unc,
    const unsigned* __restrict__ meta, unsigned* __restrict__ cntL, unsigned* __restrict__ cntE,
    unsigned* __restrict__ offL, unsigned* __restrict__ offE, unsigned* __restrict__ done)
{
    int b = blockIdx.y, blk = blockIdx.x, t = threadIdx.x;
    unsigned pivot = meta[b * 8 + 6];
    const float4* src = (const float4*)(unc + (size_t)b * HW_IMG + blk * 1024);
    float4 v = src[t];
    unsigned k0 = f2key(v.x), k1 = f2key(v.y), k2 = f2key(v.z), k3 = f2key(v.w);
    unsigned cl = (k0 < pivot) + (k1 < pivot) + (k2 < pivot) + (k3 < pivot);
    unsigned ce = (k0 == pivot) + (k1 == pivot) + (k2 == pivot) + (k3 == pivot);
    __shared__ unsigned rl[256], re[256];
    rl[t] = cl; re[t] = ce; __syncthreads();
    for (int s = 128; s > 0; s >>= 1) { if (t < s) { rl[t] += rl[t + s]; re[t] += re[t + s]; } __syncthreads(); }
    if (t == 0) { cntL[b * 256 + blk] = rl[0]; cntE[b * 256 + blk] = re[0]; }
    if (last_block(done, b, gridDim.x, t)) {
        // parallel exclusive scan of the 256 block counts (reuse rl/re)
        unsigned vL = cntL[b * 256 + t], vE = cntE[b * 256 + t];
        rl[t] = vL; re[t] = vE;
        __syncthreads();
        for (int off = 1; off < 256; off <<= 1) {
            unsigned aL = (t >= off) ? rl[t - off] : 0u;
            unsigned aE = (t >= off) ? re[t - off] : 0u;
            __syncthreads();
            rl[t] += aL; re[t] += aE;
            __syncthreads();
        }
        offL[b * 256 + t] = rl[t] - vL;
        offE[b * 256 + t] = re[t] - vE;
    }
}

__global__ __launch_bounds__(256) void k_emit(const float* __restrict__ unc,
    const unsigned* __restrict__ meta, const unsigned* __restrict__ offL,
    const unsigned* __restrict__ offE, unsigned* __restrict__ sel)
{
    int b = blockIdx.y, blk = blockIdx.x, t = threadIdx.x;
    unsigned pivot = meta[b * 8 + 6], cless = meta[b * 8 + 5], r = KSEL - cless;
    int base = blk * 1024 + t * 4;
    const float4* src = (const float4*)(unc + (size_t)b * HW_IMG + blk * 1024);
    float4 v = src[t];
    unsigned key[4] = { f2key(v.x), f2key(v.y), f2key(v.z), f2key(v.w) };
    unsigned cl = 0, ce = 0;
#pragma unroll
    for (int j = 0; j < 4; j++) { cl += (key[j] < pivot); ce += (key[j] == pivot); }
    __shared__ unsigned sL[256], sE[256];
    sL[t] = cl; sE[t] = ce; __syncthreads();
    for (int off = 1; off < 256; off <<= 1) {
        unsigned aL = (t >= off) ? sL[t - off] : 0u;
        unsigned aE = (t >= off) ? sE[t - off] : 0u;
        __syncthreads();
        sL[t] += aL; sE[t] += aE;
        __syncthreads();
    }
    unsigned posL = offL[b * 256 + blk] + sL[t] - cl;
    unsigned posE = offE[b * 256 + blk] + sE[t] - ce;
    unsigned* sb = sel + (size_t)b * KSEL;
#pragma unroll
    for (int j = 0; j < 4; j++) {
        if (key[j] < pivot) { sb[posL++] = (unsigned)(base + j); }
        else if (key[j] == pivot) { if (posE < r) sb[cless + posE] = (unsigned)(base + j); posE++; }
    }
}

// ---------------- fused gather + MLP + scatter ----------------
__global__ __launch_bounds__(256, 3) void k_main(
    const unsigned* __restrict__ sel, const float* __restrict__ prev,
    const unsigned short* __restrict__ encT,
    const unsigned short* __restrict__ w1p, const unsigned short* __restrict__ w2p,
    const float* __restrict__ c1, const float* __restrict__ c2,
    const float* __restrict__ w3, const float* __restrict__ b3,
    float* __restrict__ out)
{
    __shared__ __align__(16) unsigned short act[64][LDACT];
    __shared__ float sPart[4][64];

    // XCD swizzle: 3280 blocks = 8 XCDs x 410; batch b lands entirely on XCD b
    int wg = blockIdx.x;
    int b  = wg & 7;
    int pbase = (wg >> 3) * 64;
    int npts = KSEL - pbase; if (npts > 64) npts = 64;
    int t = threadIdx.x;
    const unsigned* selb = sel + (size_t)b * KSEL;

    // gather: bilinear, 4 lanes per point, 64 ch each (direct sel read, no barrier)
    {
        int wv2 = t >> 6, l2 = t & 63;
        int g = l2 >> 2, sub = l2 & 3;
        int p = wv2 * 16 + g;
        int gi = pbase + p; if (gi >= KSEL) gi = KSEL - 1;
        unsigned id = selb[gi];
        int col = id & 511, row = (int)(id >> 9);
        float xf = (col - 1.5f) * 0.25f;
        float yf = (row - 1.5f) * 0.25f;
        float x0f = floorf(xf), y0f = floorf(yf);
        int x0 = (int)x0f, y0 = (int)y0f;
        float wx = xf - x0f, wy = yf - y0f;
        float wxa = (x0 >= 0) ? (1.f - wx) : 0.f;
        float wxb = (x0 <= 126) ? wx : 0.f;
        float wya = (y0 >= 0) ? (1.f - wy) : 0.f;
        float wyb = (y0 <= 126) ? wy : 0.f;
        int xc0 = x0 < 0 ? 0 : x0;
        int xc1 = (x0 + 1 > 127) ? 127 : x0 + 1;
        int yc0 = y0 < 0 ? 0 : y0;
        int yc1 = (y0 + 1 > 127) ? 127 : y0 + 1;
        float w00 = wxa * wya, w10 = wxb * wya, w01 = wxa * wyb, w11 = wxb * wyb;
        const unsigned short* bb = encT + (size_t)b * 16384 * CF + sub * 64;
        const unsigned short* p00 = bb + (size_t)(yc0 * 128 + xc0) * CF;
        const unsigned short* p10 = bb + (size_t)(yc0 * 128 + xc1) * CF;
        const unsigned short* p01 = bb + (size_t)(yc1 * 128 + xc0) * CF;
        const unsigned short* p11 = bb + (size_t)(yc1 * 128 + xc1) * CF;
#pragma unroll 4
        for (int ch = 0; ch < 8; ch++) {
            short8 va = *(const short8*)(p00 + ch * 8);
            short8 vb = *(const short8*)(p10 + ch * 8);
            short8 vc = *(const short8*)(p01 + ch * 8);
            short8 vd = *(const short8*)(p11 + ch * 8);
            short8 rr;
#pragma unroll
            for (int j = 0; j < 8; j++) {
                float f = w00 * bf2f((unsigned short)va[j]) + w10 * bf2f((unsigned short)vb[j])
                        + w01 * bf2f((unsigned short)vc[j]) + w11 * bf2f((unsigned short)vd[j]);
                rr[j] = (short)f2bf(f);
            }
            *(short8*)&act[p][ACOL(sub * 64 + ch * 8)] = rr;
        }
    }
    // coarse feature + zero K-padding (cols 256..287, ACOL identity there)
    if (t < 64) {
        int gi = pbase + t; if (gi >= KSEL) gi = KSEL - 1;
        unsigned id = selb[gi];
        float cv = prev[(size_t)b * HW_IMG + id];
        short8 z = {0,0,0,0,0,0,0,0};
        short8 c8 = z; c8[0] = (short)f2bf(cv);
        *(short8*)&act[t][256] = c8;
        *(short8*)&act[t][264] = z;
        *(short8*)&act[t][272] = z;
        *(short8*)&act[t][280] = z;
    }
    __syncthreads();

    int wv = t >> 6, l = t & 63;
    int lr = l & 15, lk = l >> 4;
    f32x4 acc[4][4];
#pragma unroll
    for (int m = 0; m < 4; m++)
#pragma unroll
        for (int n = 0; n < 4; n++) acc[m][n] = (f32x4){0.f, 0.f, 0.f, 0.f};

    // layer 1: 256 x 288 (K padded)
#pragma unroll
    for (int kk = 0; kk < 9; kk++) {
        int k0 = kk * 32 + lk * 8;
        int k0s = ACOL(k0);
        short8 afr[4], bfr[4];
#pragma unroll
        for (int m = 0; m < 4; m++)
            afr[m] = *(const short8*)(w1p + (size_t)(wv * 64 + m * 16 + lr) * LDW1 + k0);
#pragma unroll
        for (int n = 0; n < 4; n++)
            bfr[n] = *(const short8*)&act[n * 16 + lr][k0s];
#pragma unroll
        for (int m = 0; m < 4; m++)
#pragma unroll
            for (int n = 0; n < 4; n++)
                acc[m][n] = __builtin_amdgcn_mfma_f32_16x16x32_bf16(afr[m], bfr[n], acc[m][n], 0, 0, 0);
    }
    __syncthreads();   // everyone done reading act before overwrite

    // epilogue L1: bias + relu + bf16, write transposed into act (cols 0..255)
#pragma unroll
    for (int m = 0; m < 4; m++) {
        int chb = wv * 64 + m * 16 + lk * 4;
        int chbs = ACOL(chb);
        float c0 = c1[chb], cA = c1[chb + 1], cB = c1[chb + 2], cC = c1[chb + 3];
#pragma unroll
        for (int n = 0; n < 4; n++) {
            int p = n * 16 + lr;
            float v0 = fmaxf(acc[m][n][0] + c0, 0.f);
            float v1 = fmaxf(acc[m][n][1] + cA, 0.f);
            float v2 = fmaxf(acc[m][n][2] + cB, 0.f);
            float v3 = fmaxf(acc[m][n][3] + cC, 0.f);
            u32x2 pk;
            pk[0] = (unsigned)f2bf(v0) | ((unsigned)f2bf(v1) << 16);
            pk[1] = (unsigned)f2bf(v2) | ((unsigned)f2bf(v3) << 16);
            *(u32x2*)&act[p][chbs] = pk;
        }
    }
    __syncthreads();

    // layer 2: 256 x 256
#pragma unroll
    for (int m = 0; m < 4; m++)
#pragma unroll
        for (int n = 0; n < 4; n++) acc[m][n] = (f32x4){0.f, 0.f, 0.f, 0.f};
#pragma unroll
    for (int kk = 0; kk < 8; kk++) {
        int k0 = kk * 32 + lk * 8;
        int k0s = ACOL(k0);
        short8 afr[4], bfr[4];
#pragma unroll
        for (int m = 0; m < 4; m++)
            afr[m] = *(const short8*)(w2p + (size_t)(wv * 64 + m * 16 + lr) * 256 + k0);
#pragma unroll
        for (int n = 0; n < 4; n++)
            bfr[n] = *(const short8*)&act[n * 16 + lr][k0s];
#pragma unroll
        for (int m = 0; m < 4; m++)
#pragma unroll
            for (int n = 0; n < 4; n++)
                acc[m][n] = __builtin_amdgcn_mfma_f32_16x16x32_bf16(afr[m], bfr[n], acc[m][n], 0, 0, 0);
    }

    // layer 3: per-lane partial dot over this wave's 64 channels
    float part[4] = {0.f, 0.f, 0.f, 0.f};
#pragma unroll
    for (int m = 0; m < 4; m++) {
        int chb = wv * 64 + m * 16 + lk * 4;
#pragma unroll
        for (int r = 0; r < 4; r++) {
            float wr = w3[chb + r];
            float cr = c2[chb + r];
#pragma unroll
            for (int n = 0; n < 4; n++)
                part[n] += wr * fmaxf(acc[m][n][r] + cr, 0.f);
        }
    }
#pragma unroll
    for (int n = 0; n < 4; n++) {
        part[n] += __shfl_xor(part[n], 16);
        part[n] += __shfl_xor(part[n], 32);
    }
    if (lk == 0) {
#pragma unroll
        for (int n = 0; n < 4; n++) sPart[wv][n * 16 + lr] = part[n];
    }
    __syncthreads();
    if (t < 64 && t < npts) {
        float tot = sPart[0][t] + sPart[1][t] + sPart[2][t] + sPart[3][t] + b3[0];
        float refined = 1.f / (1.f + __expf(-tot));
        unsigned id = selb[pbase + t];
        out[(size_t)b * HW_IMG + id] = refined;
    }
}

extern "C" void kernel_launch(void* const* d_in, const int* in_sizes, int n_in,
                              void* d_out, int out_size, void* d_ws, size_t ws_size,
                              hipStream_t stream)
{
    (void)in_sizes; (void)n_in; (void)out_size; (void)ws_size;
    const float* unc  = (const float*)d_in[0];
    const float* prev = (const float*)d_in[1];
    const float* enc  = (const float*)d_in[2];
    const float* w1   = (const float*)d_in[3];
    const float* b1   = (const float*)d_in[4];
    const float* g1   = (const float*)d_in[5];
    const float* be1  = (const float*)d_in[6];
    const float* m1   = (const float*)d_in[7];
    const float* v1   = (const float*)d_in[8];
    const float* w2   = (const float*)d_in[9];
    const float* b2   = (const float*)d_in[10];
    const float* g2   = (const float*)d_in[11];
    const float* be2  = (const float*)d_in[12];
    const float* m2   = (const float*)d_in[13];
    const float* v2   = (const float*)d_in[14];
    const float* w3   = (const float*)d_in[15];
    const float* b3   = (const float*)d_in[16];
    float* out = (float*)d_out;

    char* ws = (char*)d_ws;
    size_t off = 0;
    auto alloc = [&](size_t bytes) { size_t o = off; off += (bytes + 255) & ~(size_t)255; return o; };
    size_t o_encT = alloc((size_t)NB * 16384 * CF * 2);       // 67.1 MB
    size_t o_w1p  = alloc((size_t)256 * LDW1 * 2);
    size_t o_w2p  = alloc((size_t)256 * 256 * 2);
    size_t o_c1   = alloc(256 * 4);
    size_t o_c2   = alloc(256 * 4);
    size_t histBytes = (size_t)3 * NB * 4096 * 4;
    size_t o_hist = alloc(histBytes + 4 * NB * 4);            // hists + 4 done-counter arrays
    size_t o_meta = alloc(NB * 8 * 4);
    size_t o_cntL = alloc(NB * 256 * 4);
    size_t o_cntE = alloc(NB * 256 * 4);
    size_t o_offL = alloc(NB * 256 * 4);
    size_t o_offE = alloc(NB * 256 * 4);
    size_t o_sel  = alloc((size_t)NB * KSEL * 4);

    unsigned short* encT = (unsigned short*)(ws + o_encT);
    unsigned short* w1p  = (unsigned short*)(ws + o_w1p);
    unsigned short* w2p  = (unsigned short*)(ws + o_w2p);
    float* c1p = (float*)(ws + o_c1);
    float* c2p = (float*)(ws + o_c2);
    unsigned* histA = (unsigned*)(ws + o_hist);
    unsigned* histB = histA + (size_t)NB * 4096;
    unsigned* histC = histB + (size_t)NB * 4096;
    unsigned* doneA = histC + (size_t)NB * 4096;
    unsigned* doneB = doneA + NB;
    unsigned* doneC = doneB + NB;
    unsigned* doneN = doneC + NB;
    unsigned* meta  = (unsigned*)(ws + o_meta);
    unsigned* cntL  = (unsigned*)(ws + o_cntL);
    unsigned* cntE  = (unsigned*)(ws + o_cntE);
    unsigned* offL  = (unsigned*)(ws + o_offL);
    unsigned* offE  = (unsigned*)(ws + o_offE);
    unsigned* sel   = (unsigned*)(ws + o_sel);

    hipMemsetAsync(ws + o_hist, 0, histBytes + 4 * NB * 4, stream);
    hipMemcpyAsync(d_out, (const void*)prev, (size_t)NB * HW_IMG * 4, hipMemcpyDeviceToDevice, stream);

    k_prep<<<544, 256, 0, stream>>>(w1, w2, b1, g1, be1, m1, v1, b2, g2, be2, m2, v2,
                                    w1p, w2p, c1p, c2p);
    k_transpose<<<dim3(256, 4, NB), 256, 0, stream>>>(enc, encT);

    k_histA<<<dim3(64, NB), 256, 0, stream>>>(unc, histA, meta, doneA);
    k_histB<<<dim3(64, NB), 256, 0, stream>>>(unc, meta, histB, meta, doneB);
    k_histC<<<dim3(64, NB), 256, 0, stream>>>(unc, meta, histC, meta, doneC);
    k_count<<<dim3(256, NB), 256, 0, stream>>>(unc, meta, cntL, cntE, offL, offE, doneN);
    k_emit <<<dim3(256, NB), 256, 0, stream>>>(unc, meta, offL, offE, sel);

    k_main<<<NBLK_MAIN * NB, 256, 0, stream>>>(sel, prev, encT, w1p, w2p,
                                               c1p, c2p, w3, b3, out);
}

// Round 4
// 323.022 us; speedup vs baseline: 1.4103x; 1.4103x over previous
//
#include <hip/hip_runtime.h>
#include <hip/hip_bf16.h>

#define HW_IMG 262144   // 512*512
#define KSEL   26214    // HW_IMG/10
#define NB     8
#define CF     256
#define LDW1   288      // layer-1 K padded (257 -> 288, mult of 32)
#define LDACT  296      // LDS activation row stride (elements)
#define NBLK_MAIN 410   // tiles (64 pts) per batch
#define NPTS_PAD 26240  // 410*64

// column swizzle for act: XOR element-index bits 4-5 with bits 6-7.
// gather/stage writes 2-way, MFMA B-reads 2-way, epilogue 2-way. Bijective on
// [0,256), identity on [256,288).
#define ACOL(c) ((c) ^ ((((c) >> 6) & 3) << 4))

typedef short    short8 __attribute__((ext_vector_type(8)));
typedef float    f32x4  __attribute__((ext_vector_type(4)));
typedef unsigned u32x2  __attribute__((ext_vector_type(2)));
typedef unsigned short u16x4 __attribute__((ext_vector_type(4)));

__device__ __forceinline__ unsigned f2key(float f){
    unsigned u = __builtin_bit_cast(unsigned, f);
    return (u & 0x80000000u) ? ~u : (u | 0x80000000u);
}
__device__ __forceinline__ unsigned short f2bf(float f){
    unsigned u = __builtin_bit_cast(unsigned, f);
    u = u + 0x7FFFu + ((u >> 16) & 1u);
    return (unsigned short)(u >> 16);
}
__device__ __forceinline__ float bf2f(unsigned short s){
    unsigned u = ((unsigned)s) << 16;
    return __builtin_bit_cast(float, u);
}

// ---------------- weight prep: fold BN, convert to bf16 ----------------
__global__ __launch_bounds__(256) void k_prep(
    const float* __restrict__ w1, const float* __restrict__ w2,
    const float* __restrict__ b1, const float* __restrict__ g1, const float* __restrict__ be1,
    const float* __restrict__ m1, const float* __restrict__ v1,
    const float* __restrict__ b2, const float* __restrict__ g2, const float* __restrict__ be2,
    const float* __restrict__ m2, const float* __restrict__ v2,
    unsigned short* __restrict__ w1p, unsigned short* __restrict__ w2p,
    float* __restrict__ c1, float* __restrict__ c2)
{
    int tid = blockIdx.x * 256 + threadIdx.x;
    if (tid < 256 * LDW1) {
        int o = tid / LDW1, k = tid % LDW1;
        float scale = g1[o] * rsqrtf(v1[o] + 1e-5f);
        float val = 0.f;
        if (k < 256) val = w1[o * 257 + k + 1];   // fine channel k <- w1 col k+1
        else if (k == 256) val = w1[o * 257];     // coarse <- w1 col 0
        w1p[tid] = f2bf(val * scale);
        if (k == 0) c1[o] = (b1[o] - m1[o]) * scale + be1[o];
    } else {
        int t2 = tid - 256 * LDW1;
        if (t2 < 65536) {
            int o = t2 >> 8;
            float scale = g2[o] * rsqrtf(v2[o] + 1e-5f);
            w2p[t2] = f2bf(w2[t2] * scale);
            if ((t2 & 255) == 0) c2[o] = (b2[o] - m2[o]) * scale + be2[o];
        }
    }
}

// ---------------- enc_f transpose: [B,C,128,128] f32 -> [B,pix,C] bf16 ----------------
__global__ __launch_bounds__(256) void k_transpose(
    const float* __restrict__ enc, unsigned short* __restrict__ encT)
{
    __shared__ __align__(16) unsigned short tile[64][72];
    int b = blockIdx.z;
    int pixbase = blockIdx.x * 64;
    int chbase  = blockIdx.y * 64;
    int t = threadIdx.x;
    int pix = t & 63, cg = t >> 6;
    const float* src = enc + (size_t)b * CF * 16384;
#pragma unroll
    for (int i = 0; i < 16; i++) {
        int c = chbase + cg * 16 + i;
        tile[pix][cg * 16 + i] = f2bf(src[(size_t)c * 16384 + pixbase + pix]);
    }
    __syncthreads();
    unsigned short* dst = encT + (size_t)b * 16384 * CF;
#pragma unroll
    for (int pass = 0; pass < 4; pass++) {
        int pl = pass * 16 + (t >> 4);
        int c4 = (t & 15) * 4;
        *(u16x4*)(dst + (size_t)(pixbase + pl) * CF + chbase + c4) = *(const u16x4*)&tile[pl][c4];
    }
}

// ---------------- selection: 12/12/8-bit radix select, LDS-privatized hists ----------------
// meta per batch: [0]=binA [1]=baseA [2]=binB [3]=baseB [4]=binC [5]=cless [6]=pivot

__global__ __launch_bounds__(256) void k_histA(const float* __restrict__ unc, unsigned* __restrict__ hist)
{
    __shared__ unsigned lh[4][4096];   // per-wave private copies (64 KB)
    int b = blockIdx.y, t = threadIdx.x;
    int wv = t >> 6;
    for (int i = t; i < 4 * 4096; i += 256) ((unsigned*)lh)[i] = 0;
    __syncthreads();
    const float4* src = (const float4*)(unc + (size_t)b * HW_IMG + blockIdx.x * 4096);
    unsigned* mine = lh[wv];
#pragma unroll
    for (int j = 0; j < 4; j++) {
        float4 v = src[j * 256 + t];
        atomicAdd(&mine[f2key(v.x) >> 20], 1u);
        atomicAdd(&mine[f2key(v.y) >> 20], 1u);
        atomicAdd(&mine[f2key(v.z) >> 20], 1u);
        atomicAdd(&mine[f2key(v.w) >> 20], 1u);
    }
    __syncthreads();
    unsigned* gh = hist + (size_t)b * 4096;
    for (int i = t; i < 4096; i += 256) {
        unsigned c = lh[0][i] + lh[1][i] + lh[2][i] + lh[3][i];
        if (c) atomicAdd(&gh[i], c);
    }
}

__global__ __launch_bounds__(256) void k_histB(const float* __restrict__ unc,
    const unsigned* __restrict__ meta, unsigned* __restrict__ hist)
{
    __shared__ unsigned lh[4096];
    int b = blockIdx.y, t = threadIdx.x;
    unsigned binA = meta[b * 8 + 0];
    for (int i = t; i < 4096; i += 256) lh[i] = 0;
    __syncthreads();
    const float4* src = (const float4*)(unc + (size_t)b * HW_IMG + blockIdx.x * 4096);
#pragma unroll
    for (int j = 0; j < 4; j++) {
        float4 v = src[j * 256 + t];
        unsigned k;
        k = f2key(v.x); if ((k >> 20) == binA) atomicAdd(&lh[(k >> 8) & 0xFFFu], 1u);
        k = f2key(v.y); if ((k >> 20) == binA) atomicAdd(&lh[(k >> 8) & 0xFFFu], 1u);
        k = f2key(v.z); if ((k >> 20) == binA) atomicAdd(&lh[(k >> 8) & 0xFFFu], 1u);
        k = f2key(v.w); if ((k >> 20) == binA) atomicAdd(&lh[(k >> 8) & 0xFFFu], 1u);
    }
    __syncthreads();
    unsigned* gh = hist + (size_t)b * 4096;
    for (int i = t; i < 4096; i += 256) { unsigned c = lh[i]; if (c) atomicAdd(&gh[i], c); }
}

__global__ __launch_bounds__(256) void k_histC(const float* __restrict__ unc,
    const unsigned* __restrict__ meta, unsigned* __restrict__ hist)
{
    __shared__ unsigned lh[256];
    int b = blockIdx.y, t = threadIdx.x;
    unsigned pre24 = (meta[b * 8 + 0] << 12) | meta[b * 8 + 2];
    lh[t] = 0;
    __syncthreads();
    const float4* src = (const float4*)(unc + (size_t)b * HW_IMG + blockIdx.x * 4096);
#pragma unroll
    for (int j = 0; j < 4; j++) {
        float4 v = src[j * 256 + t];
        unsigned k;
        k = f2key(v.x); if ((k >> 8) == pre24) atomicAdd(&lh[k & 0xFFu], 1u);
        k = f2key(v.y); if ((k >> 8) == pre24) atomicAdd(&lh[k & 0xFFu], 1u);
        k = f2key(v.z); if ((k >> 8) == pre24) atomicAdd(&lh[k & 0xFFu], 1u);
        k = f2key(v.w); if ((k >> 8) == pre24) atomicAdd(&lh[k & 0xFFu], 1u);
    }
    __syncthreads();
    unsigned* gh = hist + (size_t)b * 4096;
    unsigned c = lh[t];
    if (c) atomicAdd(&gh[t], c);
}

__global__ __launch_bounds__(256) void k_find(const unsigned* __restrict__ hist,
    unsigned* __restrict__ meta, int per, int stage)
{
    int b = blockIdx.x, t = threadIdx.x;
    const unsigned* h = hist + (size_t)b * 4096;
    unsigned base = (stage == 0) ? 0u : meta[b * 8 + 2 * stage - 1];
    __shared__ unsigned seg[256], pref[256];
    unsigned s = 0;
    for (int i = 0; i < per; i++) s += h[t * per + i];
    seg[t] = s;
    __syncthreads();
    if (t == 0) { unsigned c = base; for (int i = 0; i < 256; i++) { pref[i] = c; c += seg[i]; } }
    __syncthreads();
    if (pref[t] < KSEL && KSEL <= pref[t] + seg[t]) {
        unsigned c = pref[t];
        for (int i = 0; i < per; i++) {
            unsigned cnt = h[t * per + i];
            if (c + cnt >= KSEL) {
                unsigned bin = (unsigned)(t * per + i);
                meta[b * 8 + 2 * stage] = bin;
                meta[b * 8 + 2 * stage + 1] = c;
                if (stage == 2)
                    meta[b * 8 + 6] = (meta[b * 8 + 0] << 20) | (meta[b * 8 + 2] << 8) | bin;
                break;
            }
            c += cnt;
        }
    }
}

__global__ __launch_bounds__(256) void k_count(const float* __restrict__ unc,
    const unsigned* __restrict__ meta, unsigned* __restrict__ cntL, unsigned* __restrict__ cntE)
{
    int b = blockIdx.y, blk = blockIdx.x, t = threadIdx.x;
    unsigned pivot = meta[b * 8 + 6];
    const float4* src = (const float4*)(unc + (size_t)b * HW_IMG + blk * 1024);
    float4 v = src[t];
    unsigned k0 = f2key(v.x), k1 = f2key(v.y), k2 = f2key(v.z), k3 = f2key(v.w);
    unsigned cl = (k0 < pivot) + (k1 < pivot) + (k2 < pivot) + (k3 < pivot);
    unsigned ce = (k0 == pivot) + (k1 == pivot) + (k2 == pivot) + (k3 == pivot);
    __shared__ unsigned rl[256], re[256];
    rl[t] = cl; re[t] = ce; __syncthreads();
    for (int s = 128; s > 0; s >>= 1) { if (t < s) { rl[t] += rl[t + s]; re[t] += re[t + s]; } __syncthreads(); }
    if (t == 0) { cntL[b * 256 + blk] = rl[0]; cntE[b * 256 + blk] = re[0]; }
}

__global__ void k_scan(const unsigned* __restrict__ cntL, const unsigned* __restrict__ cntE,
                       unsigned* __restrict__ offL, unsigned* __restrict__ offE)
{
    int b = blockIdx.x;
    if (threadIdx.x == 0) {
        unsigned c = 0;
        for (int i = 0; i < 256; i++) { offL[b * 256 + i] = c; c += cntL[b * 256 + i]; }
        c = 0;
        for (int i = 0; i < 256; i++) { offE[b * 256 + i] = c; c += cntE[b * 256 + i]; }
    }
}

__global__ __launch_bounds__(256) void k_emit(const float* __restrict__ unc,
    const unsigned* __restrict__ meta, const unsigned* __restrict__ offL,
    const unsigned* __restrict__ offE, unsigned* __restrict__ sel)
{
    int b = blockIdx.y, blk = blockIdx.x, t = threadIdx.x;
    unsigned pivot = meta[b * 8 + 6], cless = meta[b * 8 + 5], r = KSEL - cless;
    int base = blk * 1024 + t * 4;
    const float4* src = (const float4*)(unc + (size_t)b * HW_IMG + blk * 1024);
    float4 v = src[t];
    unsigned key[4] = { f2key(v.x), f2key(v.y), f2key(v.z), f2key(v.w) };
    unsigned cl = 0, ce = 0;
#pragma unroll
    for (int j = 0; j < 4; j++) { cl += (key[j] < pivot); ce += (key[j] == pivot); }
    __shared__ unsigned sL[256], sE[256];
    sL[t] = cl; sE[t] = ce; __syncthreads();
    for (int off = 1; off < 256; off <<= 1) {
        unsigned aL = (t >= off) ? sL[t - off] : 0u;
        unsigned aE = (t >= off) ? sE[t - off] : 0u;
        __syncthreads();
        sL[t] += aL; sE[t] += aE;
        __syncthreads();
    }
    unsigned posL = offL[b * 256 + blk] + sL[t] - cl;
    unsigned posE = offE[b * 256 + blk] + sE[t] - ce;
    unsigned* sb = sel + (size_t)b * KSEL;
#pragma unroll
    for (int j = 0; j < 4; j++) {
        if (key[j] < pivot) { sb[posL++] = (unsigned)(base + j); }
        else if (key[j] == pivot) { if (posE < r) sb[cless + posE] = (unsigned)(base + j); posE++; }
    }
}

// ---------------- decoupled gather: bilinear taps -> gout [B][NPTS_PAD][256] bf16 ----------------
__global__ __launch_bounds__(256) void k_gather(
    const unsigned* __restrict__ sel, const unsigned short* __restrict__ encT,
    unsigned short* __restrict__ gout)
{
    // XCD pinning: blocks with wg%8==b land on XCD b; batch b's encT slice stays L2-hot
    int wg = blockIdx.x;
    int b  = wg & 7;
    int pbase = (wg >> 3) * 64;
    int t = threadIdx.x;
    const unsigned* selb = sel + (size_t)b * KSEL;

    int wv2 = t >> 6, l2 = t & 63;
    int g = l2 >> 2, sub = l2 & 3;
    int p = wv2 * 16 + g;
    int gi = pbase + p; if (gi >= KSEL) gi = KSEL - 1;
    unsigned id = selb[gi];
    int col = id & 511, row = (int)(id >> 9);
    float xf = (col - 1.5f) * 0.25f;
    float yf = (row - 1.5f) * 0.25f;
    float x0f = floorf(xf), y0f = floorf(yf);
    int x0 = (int)x0f, y0 = (int)y0f;
    float wx = xf - x0f, wy = yf - y0f;
    float wxa = (x0 >= 0) ? (1.f - wx) : 0.f;
    float wxb = (x0 <= 126) ? wx : 0.f;
    float wya = (y0 >= 0) ? (1.f - wy) : 0.f;
    float wyb = (y0 <= 126) ? wy : 0.f;
    int xc0 = x0 < 0 ? 0 : x0;
    int xc1 = (x0 + 1 > 127) ? 127 : x0 + 1;
    int yc0 = y0 < 0 ? 0 : y0;
    int yc1 = (y0 + 1 > 127) ? 127 : y0 + 1;
    float w00 = wxa * wya, w10 = wxb * wya, w01 = wxa * wyb, w11 = wxb * wyb;
    const unsigned short* bb = encT + (size_t)b * 16384 * CF + sub * 64;
    const unsigned short* p00 = bb + (size_t)(yc0 * 128 + xc0) * CF;
    const unsigned short* p10 = bb + (size_t)(yc0 * 128 + xc1) * CF;
    const unsigned short* p01 = bb + (size_t)(yc1 * 128 + xc0) * CF;
    const unsigned short* p11 = bb + (size_t)(yc1 * 128 + xc1) * CF;
    unsigned short* dst = gout + ((size_t)b * NPTS_PAD + pbase + p) * CF + sub * 64;
#pragma unroll 4
    for (int ch = 0; ch < 8; ch++) {
        short8 va = *(const short8*)(p00 + ch * 8);
        short8 vb = *(const short8*)(p10 + ch * 8);
        short8 vc = *(const short8*)(p01 + ch * 8);
        short8 vd = *(const short8*)(p11 + ch * 8);
        short8 rr;
#pragma unroll
        for (int j = 0; j < 8; j++) {
            float f = w00 * bf2f((unsigned short)va[j]) + w10 * bf2f((unsigned short)vb[j])
                    + w01 * bf2f((unsigned short)vc[j]) + w11 * bf2f((unsigned short)vd[j]);
            rr[j] = (short)f2bf(f);
        }
        *(short8*)(dst + ch * 8) = rr;
    }
}

// ---------------- MLP + scatter (reads gout, stages to LDS, MFMA) ----------------
__global__ __launch_bounds__(256, 4) void k_mlp(
    const unsigned* __restrict__ sel, const float* __restrict__ prev,
    const unsigned short* __restrict__ gout,
    const unsigned short* __restrict__ w1p, const unsigned short* __restrict__ w2p,
    const float* __restrict__ c1, const float* __restrict__ c2,
    const float* __restrict__ w3, const float* __restrict__ b3,
    float* __restrict__ out)
{
    __shared__ __align__(16) unsigned short act[64][LDACT];
    __shared__ float sPart[4][64];

    int wg = blockIdx.x;
    int b  = wg & 7;
    int pbase = (wg >> 3) * 64;
    int npts = KSEL - pbase; if (npts > 64) npts = 64;
    int t = threadIdx.x;
    const unsigned* selb = sel + (size_t)b * KSEL;

    // stage gathered tile: linear coalesced global read -> swizzled LDS write
    const unsigned short* src = gout + ((size_t)b * NPTS_PAD + pbase) * CF;
#pragma unroll
    for (int i = 0; i < 8; i++) {
        int e = i * 2048 + t * 8;           // e < 16384
        short8 v = *(const short8*)(src + e);
        int pp = e >> 8, c = e & 255;
        *(short8*)&act[pp][ACOL(c)] = v;
    }
    // coarse feature + zero K-padding (cols 256..287, ACOL identity there)
    if (t < 64) {
        int gi = pbase + t; if (gi >= KSEL) gi = KSEL - 1;
        unsigned id = selb[gi];
        float cv = prev[(size_t)b * HW_IMG + id];
        short8 z = {0,0,0,0,0,0,0,0};
        short8 c8 = z; c8[0] = (short)f2bf(cv);
        *(short8*)&act[t][256] = c8;
        *(short8*)&act[t][264] = z;
        *(short8*)&act[t][272] = z;
        *(short8*)&act[t][280] = z;
    }
    __syncthreads();

    int wv = t >> 6, l = t & 63;
    int lr = l & 15, lk = l >> 4;
    f32x4 acc[4][4];
#pragma unroll
    for (int m = 0; m < 4; m++)
#pragma unroll
        for (int n = 0; n < 4; n++) acc[m][n] = (f32x4){0.f, 0.f, 0.f, 0.f};

    // layer 1: 256 x 288 (K padded)
#pragma unroll
    for (int kk = 0; kk < 9; kk++) {
        int k0 = kk * 32 + lk * 8;
        int k0s = ACOL(k0);
        short8 afr[4], bfr[4];
#pragma unroll
        for (int m = 0; m < 4; m++)
            afr[m] = *(const short8*)(w1p + (size_t)(wv * 64 + m * 16 + lr) * LDW1 + k0);
#pragma unroll
        for (int n = 0; n < 4; n++)
            bfr[n] = *(const short8*)&act[n * 16 + lr][k0s];
#pragma unroll
        for (int m = 0; m < 4; m++)
#pragma unroll
            for (int n = 0; n < 4; n++)
                acc[m][n] = __builtin_amdgcn_mfma_f32_16x16x32_bf16(afr[m], bfr[n], acc[m][n], 0, 0, 0);
    }
    __syncthreads();   // everyone done reading act before overwrite

    // epilogue L1: bias + relu + bf16, write transposed into act (cols 0..255)
#pragma unroll
    for (int m = 0; m < 4; m++) {
        int chb = wv * 64 + m * 16 + lk * 4;
        int chbs = ACOL(chb);
        float c0 = c1[chb], cA = c1[chb + 1], cB = c1[chb + 2], cC = c1[chb + 3];
#pragma unroll
        for (int n = 0; n < 4; n++) {
            int p = n * 16 + lr;
            float v0 = fmaxf(acc[m][n][0] + c0, 0.f);
            float v1 = fmaxf(acc[m][n][1] + cA, 0.f);
            float v2 = fmaxf(acc[m][n][2] + cB, 0.f);
            float v3 = fmaxf(acc[m][n][3] + cC, 0.f);
            u32x2 pk;
            pk[0] = (unsigned)f2bf(v0) | ((unsigned)f2bf(v1) << 16);
            pk[1] = (unsigned)f2bf(v2) | ((unsigned)f2bf(v3) << 16);
            *(u32x2*)&act[p][chbs] = pk;
        }
    }
    __syncthreads();

    // layer 2: 256 x 256
#pragma unroll
    for (int m = 0; m < 4; m++)
#pragma unroll
        for (int n = 0; n < 4; n++) acc[m][n] = (f32x4){0.f, 0.f, 0.f, 0.f};
#pragma unroll
    for (int kk = 0; kk < 8; kk++) {
        int k0 = kk * 32 + lk * 8;
        int k0s = ACOL(k0);
        short8 afr[4], bfr[4];
#pragma unroll
        for (int m = 0; m < 4; m++)
            afr[m] = *(const short8*)(w2p + (size_t)(wv * 64 + m * 16 + lr) * 256 + k0);
#pragma unroll
        for (int n = 0; n < 4; n++)
            bfr[n] = *(const short8*)&act[n * 16 + lr][k0s];
#pragma unroll
        for (int m = 0; m < 4; m++)
#pragma unroll
            for (int n = 0; n < 4; n++)
                acc[m][n] = __builtin_amdgcn_mfma_f32_16x16x32_bf16(afr[m], bfr[n], acc[m][n], 0, 0, 0);
    }

    // layer 3: per-lane partial dot over this wave's 64 channels
    float part[4] = {0.f, 0.f, 0.f, 0.f};
#pragma unroll
    for (int m = 0; m < 4; m++) {
        int chb = wv * 64 + m * 16 + lk * 4;
#pragma unroll
        for (int r = 0; r < 4; r++) {
            float wr = w3[chb + r];
            float cr = c2[chb + r];
#pragma unroll
            for (int n = 0; n < 4; n++)
                part[n] += wr * fmaxf(acc[m][n][r] + cr, 0.f);
        }
    }
#pragma unroll
    for (int n = 0; n < 4; n++) {
        part[n] += __shfl_xor(part[n], 16);
        part[n] += __shfl_xor(part[n], 32);
    }
    if (lk == 0) {
#pragma unroll
        for (int n = 0; n < 4; n++) sPart[wv][n * 16 + lr] = part[n];
    }
    __syncthreads();
    if (t < 64 && t < npts) {
        float tot = sPart[0][t] + sPart[1][t] + sPart[2][t] + sPart[3][t] + b3[0];
        float refined = 1.f / (1.f + __expf(-tot));
        unsigned id = selb[pbase + t];
        out[(size_t)b * HW_IMG + id] = refined;
    }
}

extern "C" void kernel_launch(void* const* d_in, const int* in_sizes, int n_in,
                              void* d_out, int out_size, void* d_ws, size_t ws_size,
                              hipStream_t stream)
{
    (void)in_sizes; (void)n_in; (void)out_size; (void)ws_size;
    const float* unc  = (const float*)d_in[0];
    const float* prev = (const float*)d_in[1];
    const float* enc  = (const float*)d_in[2];
    const float* w1   = (const float*)d_in[3];
    const float* b1   = (const float*)d_in[4];
    const float* g1   = (const float*)d_in[5];
    const float* be1  = (const float*)d_in[6];
    const float* m1   = (const float*)d_in[7];
    const float* v1   = (const float*)d_in[8];
    const float* w2   = (const float*)d_in[9];
    const float* b2   = (const float*)d_in[10];
    const float* g2   = (const float*)d_in[11];
    const float* be2  = (const float*)d_in[12];
    const float* m2   = (const float*)d_in[13];
    const float* v2   = (const float*)d_in[14];
    const float* w3   = (const float*)d_in[15];
    const float* b3   = (const float*)d_in[16];
    float* out = (float*)d_out;

    char* ws = (char*)d_ws;
    size_t off = 0;
    auto alloc = [&](size_t bytes) { size_t o = off; off += (bytes + 255) & ~(size_t)255; return o; };
    size_t o_encT = alloc((size_t)NB * 16384 * CF * 2);       // 67.1 MB
    size_t o_gout = alloc((size_t)NB * NPTS_PAD * CF * 2);    // 107.5 MB
    size_t o_w1p  = alloc((size_t)256 * LDW1 * 2);
    size_t o_w2p  = alloc((size_t)256 * 256 * 2);
    size_t o_c1   = alloc(256 * 4);
    size_t o_c2   = alloc(256 * 4);
    size_t o_hist = alloc((size_t)3 * NB * 4096 * 4);         // histA/B/C
    size_t o_meta = alloc(NB * 8 * 4);
    size_t o_cntL = alloc(NB * 256 * 4);
    size_t o_cntE = alloc(NB * 256 * 4);
    size_t o_offL = alloc(NB * 256 * 4);
    size_t o_offE = alloc(NB * 256 * 4);
    size_t o_sel  = alloc((size_t)NB * KSEL * 4);

    unsigned short* encT = (unsigned short*)(ws + o_encT);
    unsigned short* goutp= (unsigned short*)(ws + o_gout);
    unsigned short* w1p  = (unsigned short*)(ws + o_w1p);
    unsigned short* w2p  = (unsigned short*)(ws + o_w2p);
    float* c1p = (float*)(ws + o_c1);
    float* c2p = (float*)(ws + o_c2);
    unsigned* histA = (unsigned*)(ws + o_hist);
    unsigned* histB = histA + (size_t)NB * 4096;
    unsigned* histC = histB + (size_t)NB * 4096;
    unsigned* meta  = (unsigned*)(ws + o_meta);
    unsigned* cntL  = (unsigned*)(ws + o_cntL);
    unsigned* cntE  = (unsigned*)(ws + o_cntE);
    unsigned* offL  = (unsigned*)(ws + o_offL);
    unsigned* offE  = (unsigned*)(ws + o_offE);
    unsigned* sel   = (unsigned*)(ws + o_sel);

    hipMemsetAsync(ws + o_hist, 0, (size_t)3 * NB * 4096 * 4, stream);
    hipMemcpyAsync(d_out, (const void*)prev, (size_t)NB * HW_IMG * 4, hipMemcpyDeviceToDevice, stream);

    k_prep<<<544, 256, 0, stream>>>(w1, w2, b1, g1, be1, m1, v1, b2, g2, be2, m2, v2,
                                    w1p, w2p, c1p, c2p);
    k_transpose<<<dim3(256, 4, NB), 256, 0, stream>>>(enc, encT);

    k_histA<<<dim3(64, NB), 256, 0, stream>>>(unc, histA);
    k_find <<<NB, 256, 0, stream>>>(histA, meta, 16, 0);
    k_histB<<<dim3(64, NB), 256, 0, stream>>>(unc, meta, histB);
    k_find <<<NB, 256, 0, stream>>>(histB, meta, 16, 1);
    k_histC<<<dim3(64, NB), 256, 0, stream>>>(unc, meta, histC);
    k_find <<<NB, 256, 0, stream>>>(histC, meta, 1, 2);
    k_count<<<dim3(256, NB), 256, 0, stream>>>(unc, meta, cntL, cntE);
    k_scan <<<NB, 64, 0, stream>>>(cntL, cntE, offL, offE);
    k_emit <<<dim3(256, NB), 256, 0, stream>>>(unc, meta, offL, offE, sel);

    k_gather<<<NBLK_MAIN * NB, 256, 0, stream>>>(sel, encT, goutp);
    k_mlp   <<<NBLK_MAIN * NB, 256, 0, stream>>>(sel, prev, goutp, w1p, w2p,
                                                 c1p, c2p, w3, b3, out);
}

// Round 5
// 242.653 us; speedup vs baseline: 1.8774x; 1.3312x over previous
//
#include <hip/hip_runtime.h>
#include <hip/hip_bf16.h>

#define HW_IMG 262144   // 512*512
#define KSEL   26214    // HW_IMG/10
#define NB     8
#define CF     256
#define LDW1   288      // layer-1 K padded (257 -> 288, mult of 32)
#define LDACT  296      // LDS activation row stride (elements)
#define NBLK_MAIN 410   // tiles (64 pts) per batch
#define NPTS_PAD 26240  // 410*64

// column swizzle for act: XOR element-index bits 4-5 with bits 6-7.
// stage writes 2-way, MFMA B-reads 2-way, epilogue 2-way. Bijective on
// [0,256), identity on [256,288).
#define ACOL(c) ((c) ^ ((((c) >> 6) & 3) << 4))

typedef short    short8 __attribute__((ext_vector_type(8)));
typedef float    f32x4  __attribute__((ext_vector_type(4)));
typedef unsigned u32x2  __attribute__((ext_vector_type(2)));
typedef unsigned short u16x4 __attribute__((ext_vector_type(4)));

__device__ __forceinline__ unsigned f2key(float f){
    unsigned u = __builtin_bit_cast(unsigned, f);
    return (u & 0x80000000u) ? ~u : (u | 0x80000000u);
}
__device__ __forceinline__ unsigned short f2bf(float f){
    unsigned u = __builtin_bit_cast(unsigned, f);
    u = u + 0x7FFFu + ((u >> 16) & 1u);
    return (unsigned short)(u >> 16);
}
__device__ __forceinline__ float bf2f(unsigned short s){
    unsigned u = ((unsigned)s) << 16;
    return __builtin_bit_cast(float, u);
}

// ---------------- weight prep: fold BN, convert to bf16 ----------------
__global__ __launch_bounds__(256) void k_prep(
    const float* __restrict__ w1, const float* __restrict__ w2,
    const float* __restrict__ b1, const float* __restrict__ g1, const float* __restrict__ be1,
    const float* __restrict__ m1, const float* __restrict__ v1,
    const float* __restrict__ b2, const float* __restrict__ g2, const float* __restrict__ be2,
    const float* __restrict__ m2, const float* __restrict__ v2,
    unsigned short* __restrict__ w1p, unsigned short* __restrict__ w2p,
    float* __restrict__ c1, float* __restrict__ c2)
{
    int tid = blockIdx.x * 256 + threadIdx.x;
    if (tid < 256 * LDW1) {
        int o = tid / LDW1, k = tid % LDW1;
        float scale = g1[o] * rsqrtf(v1[o] + 1e-5f);
        float val = 0.f;
        if (k < 256) val = w1[o * 257 + k + 1];   // fine channel k <- w1 col k+1
        else if (k == 256) val = w1[o * 257];     // coarse <- w1 col 0
        w1p[tid] = f2bf(val * scale);
        if (k == 0) c1[o] = (b1[o] - m1[o]) * scale + be1[o];
    } else {
        int t2 = tid - 256 * LDW1;
        if (t2 < 65536) {
            int o = t2 >> 8;
            float scale = g2[o] * rsqrtf(v2[o] + 1e-5f);
            w2p[t2] = f2bf(w2[t2] * scale);
            if ((t2 & 255) == 0) c2[o] = (b2[o] - m2[o]) * scale + be2[o];
        }
    }
}

// ---------------- enc_f transpose: [B,C,128,128] f32 -> [B,pix,C] bf16 ----------------
__global__ __launch_bounds__(256) void k_transpose(
    const float* __restrict__ enc, unsigned short* __restrict__ encT)
{
    __shared__ __align__(16) unsigned short tile[64][72];
    int b = blockIdx.z;
    int pixbase = blockIdx.x * 64;
    int chbase  = blockIdx.y * 64;
    int t = threadIdx.x;
    int pix = t & 63, cg = t >> 6;
    const float* src = enc + (size_t)b * CF * 16384;
#pragma unroll
    for (int i = 0; i < 16; i++) {
        int c = chbase + cg * 16 + i;
        tile[pix][cg * 16 + i] = f2bf(src[(size_t)c * 16384 + pixbase + pix]);
    }
    __syncthreads();
    unsigned short* dst = encT + (size_t)b * 16384 * CF;
#pragma unroll
    for (int pass = 0; pass < 4; pass++) {
        int pl = pass * 16 + (t >> 4);
        int c4 = (t & 15) * 4;
        *(u16x4*)(dst + (size_t)(pixbase + pl) * CF + chbase + c4) = *(const u16x4*)&tile[pl][c4];
    }
}

// ---------------- selection: 12/12/8-bit radix select, LDS-privatized hists ----------------
// meta per batch: [0]=binA [1]=baseA [2]=binB [3]=baseB [4]=binC [5]=cless [6]=pivot

__global__ __launch_bounds__(256) void k_histA(const float* __restrict__ unc, unsigned* __restrict__ hist)
{
    __shared__ unsigned lh[4][4096];   // per-wave private copies (64 KB)
    int b = blockIdx.y, t = threadIdx.x;
    int wv = t >> 6;
    for (int i = t; i < 4 * 4096; i += 256) ((unsigned*)lh)[i] = 0;
    __syncthreads();
    const float4* src = (const float4*)(unc + (size_t)b * HW_IMG + blockIdx.x * 4096);
    unsigned* mine = lh[wv];
#pragma unroll
    for (int j = 0; j < 4; j++) {
        float4 v = src[j * 256 + t];
        atomicAdd(&mine[f2key(v.x) >> 20], 1u);
        atomicAdd(&mine[f2key(v.y) >> 20], 1u);
        atomicAdd(&mine[f2key(v.z) >> 20], 1u);
        atomicAdd(&mine[f2key(v.w) >> 20], 1u);
    }
    __syncthreads();
    unsigned* gh = hist + (size_t)b * 4096;
    for (int i = t; i < 4096; i += 256) {
        unsigned c = lh[0][i] + lh[1][i] + lh[2][i] + lh[3][i];
        if (c) atomicAdd(&gh[i], c);
    }
}

__global__ __launch_bounds__(256) void k_histB(const float* __restrict__ unc,
    const unsigned* __restrict__ meta, unsigned* __restrict__ hist)
{
    __shared__ unsigned lh[4096];
    int b = blockIdx.y, t = threadIdx.x;
    unsigned binA = meta[b * 8 + 0];
    for (int i = t; i < 4096; i += 256) lh[i] = 0;
    __syncthreads();
    const float4* src = (const float4*)(unc + (size_t)b * HW_IMG + blockIdx.x * 4096);
#pragma unroll
    for (int j = 0; j < 4; j++) {
        float4 v = src[j * 256 + t];
        unsigned k;
        k = f2key(v.x); if ((k >> 20) == binA) atomicAdd(&lh[(k >> 8) & 0xFFFu], 1u);
        k = f2key(v.y); if ((k >> 20) == binA) atomicAdd(&lh[(k >> 8) & 0xFFFu], 1u);
        k = f2key(v.z); if ((k >> 20) == binA) atomicAdd(&lh[(k >> 8) & 0xFFFu], 1u);
        k = f2key(v.w); if ((k >> 20) == binA) atomicAdd(&lh[(k >> 8) & 0xFFFu], 1u);
    }
    __syncthreads();
    unsigned* gh = hist + (size_t)b * 4096;
    for (int i = t; i < 4096; i += 256) { unsigned c = lh[i]; if (c) atomicAdd(&gh[i], c); }
}

__global__ __launch_bounds__(256) void k_histC(const float* __restrict__ unc,
    const unsigned* __restrict__ meta, unsigned* __restrict__ hist)
{
    __shared__ unsigned lh[256];
    int b = blockIdx.y, t = threadIdx.x;
    unsigned pre24 = (meta[b * 8 + 0] << 12) | meta[b * 8 + 2];
    lh[t] = 0;
    __syncthreads();
    const float4* src = (const float4*)(unc + (size_t)b * HW_IMG + blockIdx.x * 4096);
#pragma unroll
    for (int j = 0; j < 4; j++) {
        float4 v = src[j * 256 + t];
        unsigned k;
        k = f2key(v.x); if ((k >> 8) == pre24) atomicAdd(&lh[k & 0xFFu], 1u);
        k = f2key(v.y); if ((k >> 8) == pre24) atomicAdd(&lh[k & 0xFFu], 1u);
        k = f2key(v.z); if ((k >> 8) == pre24) atomicAdd(&lh[k & 0xFFu], 1u);
        k = f2key(v.w); if ((k >> 8) == pre24) atomicAdd(&lh[k & 0xFFu], 1u);
    }
    __syncthreads();
    unsigned* gh = hist + (size_t)b * 4096;
    unsigned c = lh[t];
    if (c) atomicAdd(&gh[t], c);
}

__global__ __launch_bounds__(256) void k_find(const unsigned* __restrict__ hist,
    unsigned* __restrict__ meta, int per, int stage)
{
    int b = blockIdx.x, t = threadIdx.x;
    const unsigned* h = hist + (size_t)b * 4096;
    unsigned base = (stage == 0) ? 0u : meta[b * 8 + 2 * stage - 1];
    __shared__ unsigned seg[256], pref[256];
    unsigned s = 0;
    for (int i = 0; i < per; i++) s += h[t * per + i];
    seg[t] = s;
    __syncthreads();
    if (t == 0) { unsigned c = base; for (int i = 0; i < 256; i++) { pref[i] = c; c += seg[i]; } }
    __syncthreads();
    if (pref[t] < KSEL && KSEL <= pref[t] + seg[t]) {
        unsigned c = pref[t];
        for (int i = 0; i < per; i++) {
            unsigned cnt = h[t * per + i];
            if (c + cnt >= KSEL) {
                unsigned bin = (unsigned)(t * per + i);
                meta[b * 8 + 2 * stage] = bin;
                meta[b * 8 + 2 * stage + 1] = c;
                if (stage == 2)
                    meta[b * 8 + 6] = (meta[b * 8 + 0] << 20) | (meta[b * 8 + 2] << 8) | bin;
                break;
            }
            c += cnt;
        }
    }
}

__global__ __launch_bounds__(256) void k_count(const float* __restrict__ unc,
    const unsigned* __restrict__ meta, unsigned* __restrict__ cntL, unsigned* __restrict__ cntE)
{
    int b = blockIdx.y, blk = blockIdx.x, t = threadIdx.x;
    unsigned pivot = meta[b * 8 + 6];
    const float4* src = (const float4*)(unc + (size_t)b * HW_IMG + blk * 1024);
    float4 v = src[t];
    unsigned k0 = f2key(v.x), k1 = f2key(v.y), k2 = f2key(v.z), k3 = f2key(v.w);
    unsigned cl = (k0 < pivot) + (k1 < pivot) + (k2 < pivot) + (k3 < pivot);
    unsigned ce = (k0 == pivot) + (k1 == pivot) + (k2 == pivot) + (k3 == pivot);
    __shared__ unsigned rl[256], re[256];
    rl[t] = cl; re[t] = ce; __syncthreads();
    for (int s = 128; s > 0; s >>= 1) { if (t < s) { rl[t] += rl[t + s]; re[t] += re[t + s]; } __syncthreads(); }
    if (t == 0) { cntL[b * 256 + blk] = rl[0]; cntE[b * 256 + blk] = re[0]; }
}

__global__ void k_scan(const unsigned* __restrict__ cntL, const unsigned* __restrict__ cntE,
                       unsigned* __restrict__ offL, unsigned* __restrict__ offE)
{
    int b = blockIdx.x;
    if (threadIdx.x == 0) {
        unsigned c = 0;
        for (int i = 0; i < 256; i++) { offL[b * 256 + i] = c; c += cntL[b * 256 + i]; }
        c = 0;
        for (int i = 0; i < 256; i++) { offE[b * 256 + i] = c; c += cntE[b * 256 + i]; }
    }
}

__global__ __launch_bounds__(256) void k_emit(const float* __restrict__ unc,
    const unsigned* __restrict__ meta, const unsigned* __restrict__ offL,
    const unsigned* __restrict__ offE, unsigned* __restrict__ sel)
{
    int b = blockIdx.y, blk = blockIdx.x, t = threadIdx.x;
    unsigned pivot = meta[b * 8 + 6], cless = meta[b * 8 + 5], r = KSEL - cless;
    int base = blk * 1024 + t * 4;
    const float4* src = (const float4*)(unc + (size_t)b * HW_IMG + blk * 1024);
    float4 v = src[t];
    unsigned key[4] = { f2key(v.x), f2key(v.y), f2key(v.z), f2key(v.w) };
    unsigned cl = 0, ce = 0;
#pragma unroll
    for (int j = 0; j < 4; j++) { cl += (key[j] < pivot); ce += (key[j] == pivot); }
    __shared__ unsigned sL[256], sE[256];
    sL[t] = cl; sE[t] = ce; __syncthreads();
    for (int off = 1; off < 256; off <<= 1) {
        unsigned aL = (t >= off) ? sL[t - off] : 0u;
        unsigned aE = (t >= off) ? sE[t - off] : 0u;
        __syncthreads();
        sL[t] += aL; sE[t] += aE;
        __syncthreads();
    }
    unsigned posL = offL[b * 256 + blk] + sL[t] - cl;
    unsigned posE = offE[b * 256 + blk] + sE[t] - ce;
    unsigned* sb = sel + (size_t)b * KSEL;
#pragma unroll
    for (int j = 0; j < 4; j++) {
        if (key[j] < pivot) { sb[posL++] = (unsigned)(base + j); }
        else if (key[j] == pivot) { if (posE < r) sb[cless + posE] = (unsigned)(base + j); posE++; }
    }
}

// ---------------- decoupled gather: bilinear taps -> gout [B][NPTS_PAD][256] bf16 ----------------
// channel interleave sub*8 + ch*32: each 4-lane point-group's store covers a
// contiguous 64B sector (fix for 4.5x HBM write amplification seen with the
// sub*64 + ch*8 mapping: 16B chunks at 128B stride -> partial-sector writebacks)
__global__ __launch_bounds__(256) void k_gather(
    const unsigned* __restrict__ sel, const unsigned short* __restrict__ encT,
    unsigned short* __restrict__ gout)
{
    // XCD pinning: blocks with wg%8==b land on XCD b; batch b's encT slice stays L2-hot
    int wg = blockIdx.x;
    int b  = wg & 7;
    int pbase = (wg >> 3) * 64;
    int t = threadIdx.x;
    const unsigned* selb = sel + (size_t)b * KSEL;

    int wv2 = t >> 6, l2 = t & 63;
    int g = l2 >> 2, sub = l2 & 3;
    int p = wv2 * 16 + g;
    int gi = pbase + p; if (gi >= KSEL) gi = KSEL - 1;
    unsigned id = selb[gi];
    int col = id & 511, row = (int)(id >> 9);
    float xf = (col - 1.5f) * 0.25f;
    float yf = (row - 1.5f) * 0.25f;
    float x0f = floorf(xf), y0f = floorf(yf);
    int x0 = (int)x0f, y0 = (int)y0f;
    float wx = xf - x0f, wy = yf - y0f;
    float wxa = (x0 >= 0) ? (1.f - wx) : 0.f;
    float wxb = (x0 <= 126) ? wx : 0.f;
    float wya = (y0 >= 0) ? (1.f - wy) : 0.f;
    float wyb = (y0 <= 126) ? wy : 0.f;
    int xc0 = x0 < 0 ? 0 : x0;
    int xc1 = (x0 + 1 > 127) ? 127 : x0 + 1;
    int yc0 = y0 < 0 ? 0 : y0;
    int yc1 = (y0 + 1 > 127) ? 127 : y0 + 1;
    float w00 = wxa * wya, w10 = wxb * wya, w01 = wxa * wyb, w11 = wxb * wyb;
    const unsigned short* bb = encT + (size_t)b * 16384 * CF;
    const unsigned short* p00 = bb + (size_t)(yc0 * 128 + xc0) * CF + sub * 8;
    const unsigned short* p10 = bb + (size_t)(yc0 * 128 + xc1) * CF + sub * 8;
    const unsigned short* p01 = bb + (size_t)(yc1 * 128 + xc0) * CF + sub * 8;
    const unsigned short* p11 = bb + (size_t)(yc1 * 128 + xc1) * CF + sub * 8;
    unsigned short* dst = gout + ((size_t)b * NPTS_PAD + pbase + p) * CF + sub * 8;
#pragma unroll 4
    for (int ch = 0; ch < 8; ch++) {
        int off = ch * 32;
        short8 va = *(const short8*)(p00 + off);
        short8 vb = *(const short8*)(p10 + off);
        short8 vc = *(const short8*)(p01 + off);
        short8 vd = *(const short8*)(p11 + off);
        short8 rr;
#pragma unroll
        for (int j = 0; j < 8; j++) {
            float f = w00 * bf2f((unsigned short)va[j]) + w10 * bf2f((unsigned short)vb[j])
                    + w01 * bf2f((unsigned short)vc[j]) + w11 * bf2f((unsigned short)vd[j]);
            rr[j] = (short)f2bf(f);
        }
        *(short8*)(dst + off) = rr;
    }
}

// ---------------- MLP + scatter (reads gout, stages to LDS, MFMA) ----------------
__global__ __launch_bounds__(256, 4) void k_mlp(
    const unsigned* __restrict__ sel, const float* __restrict__ prev,
    const unsigned short* __restrict__ gout,
    const unsigned short* __restrict__ w1p, const unsigned short* __restrict__ w2p,
    const float* __restrict__ c1, const float* __restrict__ c2,
    const float* __restrict__ w3, const float* __restrict__ b3,
    float* __restrict__ out)
{
    __shared__ __align__(16) unsigned short act[64][LDACT];
    __shared__ float sPart[4][64];

    int wg = blockIdx.x;
    int b  = wg & 7;
    int pbase = (wg >> 3) * 64;
    int npts = KSEL - pbase; if (npts > 64) npts = 64;
    int t = threadIdx.x;
    const unsigned* selb = sel + (size_t)b * KSEL;

    // stage gathered tile: linear coalesced global read -> swizzled LDS write
    const unsigned short* src = gout + ((size_t)b * NPTS_PAD + pbase) * CF;
#pragma unroll
    for (int i = 0; i < 8; i++) {
        int e = i * 2048 + t * 8;           // e < 16384
        short8 v = *(const short8*)(src + e);
        int pp = e >> 8, c = e & 255;
        *(short8*)&act[pp][ACOL(c)] = v;
    }
    // coarse feature + zero K-padding (cols 256..287, ACOL identity there)
    if (t < 64) {
        int gi = pbase + t; if (gi >= KSEL) gi = KSEL - 1;
        unsigned id = selb[gi];
        float cv = prev[(size_t)b * HW_IMG + id];
        short8 z = {0,0,0,0,0,0,0,0};
        short8 c8 = z; c8[0] = (short)f2bf(cv);
        *(short8*)&act[t][256] = c8;
        *(short8*)&act[t][264] = z;
        *(short8*)&act[t][272] = z;
        *(short8*)&act[t][280] = z;
    }
    __syncthreads();

    int wv = t >> 6, l = t & 63;
    int lr = l & 15, lk = l >> 4;
    f32x4 acc[4][4];
#pragma unroll
    for (int m = 0; m < 4; m++)
#pragma unroll
        for (int n = 0; n < 4; n++) acc[m][n] = (f32x4){0.f, 0.f, 0.f, 0.f};

    // layer 1: 256 x 288 (K padded)
#pragma unroll
    for (int kk = 0; kk < 9; kk++) {
        int k0 = kk * 32 + lk * 8;
        int k0s = ACOL(k0);
        short8 afr[4], bfr[4];
#pragma unroll
        for (int m = 0; m < 4; m++)
            afr[m] = *(const short8*)(w1p + (size_t)(wv * 64 + m * 16 + lr) * LDW1 + k0);
#pragma unroll
        for (int n = 0; n < 4; n++)
            bfr[n] = *(const short8*)&act[n * 16 + lr][k0s];
#pragma unroll
        for (int m = 0; m < 4; m++)
#pragma unroll
            for (int n = 0; n < 4; n++)
                acc[m][n] = __builtin_amdgcn_mfma_f32_16x16x32_bf16(afr[m], bfr[n], acc[m][n], 0, 0, 0);
    }
    __syncthreads();   // everyone done reading act before overwrite

    // epilogue L1: bias + relu + bf16, write transposed into act (cols 0..255)
#pragma unroll
    for (int m = 0; m < 4; m++) {
        int chb = wv * 64 + m * 16 + lk * 4;
        int chbs = ACOL(chb);
        float c0 = c1[chb], cA = c1[chb + 1], cB = c1[chb + 2], cC = c1[chb + 3];
#pragma unroll
        for (int n = 0; n < 4; n++) {
            int p = n * 16 + lr;
            float v0 = fmaxf(acc[m][n][0] + c0, 0.f);
            float v1 = fmaxf(acc[m][n][1] + cA, 0.f);
            float v2 = fmaxf(acc[m][n][2] + cB, 0.f);
            float v3 = fmaxf(acc[m][n][3] + cC, 0.f);
            u32x2 pk;
            pk[0] = (unsigned)f2bf(v0) | ((unsigned)f2bf(v1) << 16);
            pk[1] = (unsigned)f2bf(v2) | ((unsigned)f2bf(v3) << 16);
            *(u32x2*)&act[p][chbs] = pk;
        }
    }
    __syncthreads();

    // layer 2: 256 x 256
#pragma unroll
    for (int m = 0; m < 4; m++)
#pragma unroll
        for (int n = 0; n < 4; n++) acc[m][n] = (f32x4){0.f, 0.f, 0.f, 0.f};
#pragma unroll
    for (int kk = 0; kk < 8; kk++) {
        int k0 = kk * 32 + lk * 8;
        int k0s = ACOL(k0);
        short8 afr[4], bfr[4];
#pragma unroll
        for (int m = 0; m < 4; m++)
            afr[m] = *(const short8*)(w2p + (size_t)(wv * 64 + m * 16 + lr) * 256 + k0);
#pragma unroll
        for (int n = 0; n < 4; n++)
            bfr[n] = *(const short8*)&act[n * 16 + lr][k0s];
#pragma unroll
        for (int m = 0; m < 4; m++)
#pragma unroll
            for (int n = 0; n < 4; n++)
                acc[m][n] = __builtin_amdgcn_mfma_f32_16x16x32_bf16(afr[m], bfr[n], acc[m][n], 0, 0, 0);
    }

    // layer 3: per-lane partial dot over this wave's 64 channels
    float part[4] = {0.f, 0.f, 0.f, 0.f};
#pragma unroll
    for (int m = 0; m < 4; m++) {
        int chb = wv * 64 + m * 16 + lk * 4;
#pragma unroll
        for (int r = 0; r < 4; r++) {
            float wr = w3[chb + r];
            float cr = c2[chb + r];
#pragma unroll
            for (int n = 0; n < 4; n++)
                part[n] += wr * fmaxf(acc[m][n][r] + cr, 0.f);
        }
    }
#pragma unroll
    for (int n = 0; n < 4; n++) {
        part[n] += __shfl_xor(part[n], 16);
        part[n] += __shfl_xor(part[n], 32);
    }
    if (lk == 0) {
#pragma unroll
        for (int n = 0; n < 4; n++) sPart[wv][n * 16 + lr] = part[n];
    }
    __syncthreads();
    if (t < 64 && t < npts) {
        float tot = sPart[0][t] + sPart[1][t] + sPart[2][t] + sPart[3][t] + b3[0];
        float refined = 1.f / (1.f + __expf(-tot));
        unsigned id = selb[pbase + t];
        out[(size_t)b * HW_IMG + id] = refined;
    }
}

extern "C" void kernel_launch(void* const* d_in, const int* in_sizes, int n_in,
                              void* d_out, int out_size, void* d_ws, size_t ws_size,
                              hipStream_t stream)
{
    (void)in_sizes; (void)n_in; (void)out_size; (void)ws_size;
    const float* unc  = (const float*)d_in[0];
    const float* prev = (const float*)d_in[1];
    const float* enc  = (const float*)d_in[2];
    const float* w1   = (const float*)d_in[3];
    const float* b1   = (const float*)d_in[4];
    const float* g1   = (const float*)d_in[5];
    const float* be1  = (const float*)d_in[6];
    const float* m1   = (const float*)d_in[7];
    const float* v1   = (const float*)d_in[8];
    const float* w2   = (const float*)d_in[9];
    const float* b2   = (const float*)d_in[10];
    const float* g2   = (const float*)d_in[11];
    const float* be2  = (const float*)d_in[12];
    const float* m2   = (const float*)d_in[13];
    const float* v2   = (const float*)d_in[14];
    const float* w3   = (const float*)d_in[15];
    const float* b3   = (const float*)d_in[16];
    float* out = (float*)d_out;

    char* ws = (char*)d_ws;
    size_t off = 0;
    auto alloc = [&](size_t bytes) { size_t o = off; off += (bytes + 255) & ~(size_t)255; return o; };
    size_t o_encT = alloc((size_t)NB * 16384 * CF * 2);       // 67.1 MB
    size_t o_gout = alloc((size_t)NB * NPTS_PAD * CF * 2);    // 107.5 MB
    size_t o_w1p  = alloc((size_t)256 * LDW1 * 2);
    size_t o_w2p  = alloc((size_t)256 * 256 * 2);
    size_t o_c1   = alloc(256 * 4);
    size_t o_c2   = alloc(256 * 4);
    size_t o_hist = alloc((size_t)3 * NB * 4096 * 4);         // histA/B/C
    size_t o_meta = alloc(NB * 8 * 4);
    size_t o_cntL = alloc(NB * 256 * 4);
    size_t o_cntE = alloc(NB * 256 * 4);
    size_t o_offL = alloc(NB * 256 * 4);
    size_t o_offE = alloc(NB * 256 * 4);
    size_t o_sel  = alloc((size_t)NB * KSEL * 4);

    unsigned short* encT = (unsigned short*)(ws + o_encT);
    unsigned short* goutp= (unsigned short*)(ws + o_gout);
    unsigned short* w1p  = (unsigned short*)(ws + o_w1p);
    unsigned short* w2p  = (unsigned short*)(ws + o_w2p);
    float* c1p = (float*)(ws + o_c1);
    float* c2p = (float*)(ws + o_c2);
    unsigned* histA = (unsigned*)(ws + o_hist);
    unsigned* histB = histA + (size_t)NB * 4096;
    unsigned* histC = histB + (size_t)NB * 4096;
    unsigned* meta  = (unsigned*)(ws + o_meta);
    unsigned* cntL  = (unsigned*)(ws + o_cntL);
    unsigned* cntE  = (unsigned*)(ws + o_cntE);
    unsigned* offL  = (unsigned*)(ws + o_offL);
    unsigned* offE  = (unsigned*)(ws + o_offE);
    unsigned* sel   = (unsigned*)(ws + o_sel);

    hipMemsetAsync(ws + o_hist, 0, (size_t)3 * NB * 4096 * 4, stream);
    hipMemcpyAsync(d_out, (const void*)prev, (size_t)NB * HW_IMG * 4, hipMemcpyDeviceToDevice, stream);

    k_prep<<<544, 256, 0, stream>>>(w1, w2, b1, g1, be1, m1, v1, b2, g2, be2, m2, v2,
                                    w1p, w2p, c1p, c2p);
    k_transpose<<<dim3(256, 4, NB), 256, 0, stream>>>(enc, encT);

    k_histA<<<dim3(64, NB), 256, 0, stream>>>(unc, histA);
    k_find <<<NB, 256, 0, stream>>>(histA, meta, 16, 0);
    k_histB<<<dim3(64, NB), 256, 0, stream>>>(unc, meta, histB);
    k_find <<<NB, 256, 0, stream>>>(histB, meta, 16, 1);
    k_histC<<<dim3(64, NB), 256, 0, stream>>>(unc, meta, histC);
    k_find <<<NB, 256, 0, stream>>>(histC, meta, 1, 2);
    k_count<<<dim3(256, NB), 256, 0, stream>>>(unc, meta, cntL, cntE);
    k_scan <<<NB, 64, 0, stream>>>(cntL, cntE, offL, offE);
    k_emit <<<dim3(256, NB), 256, 0, stream>>>(unc, meta, offL, offE, sel);

    k_gather<<<NBLK_MAIN * NB, 256, 0, stream>>>(sel, encT, goutp);
    k_mlp   <<<NBLK_MAIN * NB, 256, 0, stream>>>(sel, prev, goutp, w1p, w2p,
                                                 c1p, c2p, w3, b3, out);
}

// Round 6
// 234.252 us; speedup vs baseline: 1.9448x; 1.0359x over previous
//
#include <hip/hip_runtime.h>
#include <hip/hip_bf16.h>

#define HW_IMG 262144   // 512*512
#define KSEL   26214    // HW_IMG/10
#define NB     8
#define CF     256
#define LDW1   288      // layer-1 K padded (257 -> 288, mult of 32)
#define LDACT  296      // LDS activation row stride (elements)
#define GBLK   410      // gather tiles (64 pts) per batch
#define MBLK   205      // mlp tiles (128 pts) per batch
#define NPTS_PAD 26240  // 410*64 = 205*128

// column swizzle for act: XOR element-index bits 4-5 with bits 6-7.
// stage writes conflict-free, MFMA B-reads 2-way, epilogue 2-way. Bijective on
// [0,256), identity on [256,288).
#define ACOL(c) ((c) ^ ((((c) >> 6) & 3) << 4))

typedef short    short8 __attribute__((ext_vector_type(8)));
typedef float    f32x4  __attribute__((ext_vector_type(4)));
typedef unsigned u32x2  __attribute__((ext_vector_type(2)));
typedef unsigned short u16x4 __attribute__((ext_vector_type(4)));

__device__ __forceinline__ unsigned f2key(float f){
    unsigned u = __builtin_bit_cast(unsigned, f);
    return (u & 0x80000000u) ? ~u : (u | 0x80000000u);
}
__device__ __forceinline__ unsigned short f2bf(float f){
    unsigned u = __builtin_bit_cast(unsigned, f);
    u = u + 0x7FFFu + ((u >> 16) & 1u);
    return (unsigned short)(u >> 16);
}
__device__ __forceinline__ float bf2f(unsigned short s){
    unsigned u = ((unsigned)s) << 16;
    return __builtin_bit_cast(float, u);
}

// ---------------- weight prep: fold BN, convert to bf16 ----------------
__global__ __launch_bounds__(256) void k_prep(
    const float* __restrict__ w1, const float* __restrict__ w2,
    const float* __restrict__ b1, const float* __restrict__ g1, const float* __restrict__ be1,
    const float* __restrict__ m1, const float* __restrict__ v1,
    const float* __restrict__ b2, const float* __restrict__ g2, const float* __restrict__ be2,
    const float* __restrict__ m2, const float* __restrict__ v2,
    unsigned short* __restrict__ w1p, unsigned short* __restrict__ w2p,
    float* __restrict__ c1, float* __restrict__ c2)
{
    int tid = blockIdx.x * 256 + threadIdx.x;
    if (tid < 256 * LDW1) {
        int o = tid / LDW1, k = tid % LDW1;
        float scale = g1[o] * rsqrtf(v1[o] + 1e-5f);
        float val = 0.f;
        if (k < 256) val = w1[o * 257 + k + 1];   // fine channel k <- w1 col k+1
        else if (k == 256) val = w1[o * 257];     // coarse <- w1 col 0
        w1p[tid] = f2bf(val * scale);
        if (k == 0) c1[o] = (b1[o] - m1[o]) * scale + be1[o];
    } else {
        int t2 = tid - 256 * LDW1;
        if (t2 < 65536) {
            int o = t2 >> 8;
            float scale = g2[o] * rsqrtf(v2[o] + 1e-5f);
            w2p[t2] = f2bf(w2[t2] * scale);
            if ((t2 & 255) == 0) c2[o] = (b2[o] - m2[o]) * scale + be2[o];
        }
    }
}

// ---------------- enc_f transpose: [B,C,128,128] f32 -> [B,pix,C] bf16 ----------------
__global__ __launch_bounds__(256) void k_transpose(
    const float* __restrict__ enc, unsigned short* __restrict__ encT)
{
    __shared__ __align__(16) unsigned short tile[64][72];
    int b = blockIdx.z;
    int pixbase = blockIdx.x * 64;
    int chbase  = blockIdx.y * 64;
    int t = threadIdx.x;
    int pix = t & 63, cg = t >> 6;
    const float* src = enc + (size_t)b * CF * 16384;
#pragma unroll
    for (int i = 0; i < 16; i++) {
        int c = chbase + cg * 16 + i;
        tile[pix][cg * 16 + i] = f2bf(src[(size_t)c * 16384 + pixbase + pix]);
    }
    __syncthreads();
    unsigned short* dst = encT + (size_t)b * 16384 * CF;
#pragma unroll
    for (int pass = 0; pass < 4; pass++) {
        int pl = pass * 16 + (t >> 4);
        int c4 = (t & 15) * 4;
        *(u16x4*)(dst + (size_t)(pixbase + pl) * CF + chbase + c4) = *(const u16x4*)&tile[pl][c4];
    }
}

// ---------------- selection: 12/12/8-bit radix select, LDS-privatized hists ----------------
// meta per batch: [0]=binA [1]=baseA [2]=binB [3]=baseB [4]=binC [5]=cless [6]=pivot

__global__ __launch_bounds__(256) void k_histA(const float* __restrict__ unc, unsigned* __restrict__ hist)
{
    __shared__ unsigned lh[4][4096];   // per-wave private copies (64 KB)
    int b = blockIdx.y, t = threadIdx.x;
    int wv = t >> 6;
    for (int i = t; i < 4 * 4096; i += 256) ((unsigned*)lh)[i] = 0;
    __syncthreads();
    const float4* src = (const float4*)(unc + (size_t)b * HW_IMG + blockIdx.x * 4096);
    unsigned* mine = lh[wv];
#pragma unroll
    for (int j = 0; j < 4; j++) {
        float4 v = src[j * 256 + t];
        atomicAdd(&mine[f2key(v.x) >> 20], 1u);
        atomicAdd(&mine[f2key(v.y) >> 20], 1u);
        atomicAdd(&mine[f2key(v.z) >> 20], 1u);
        atomicAdd(&mine[f2key(v.w) >> 20], 1u);
    }
    __syncthreads();
    unsigned* gh = hist + (size_t)b * 4096;
    for (int i = t; i < 4096; i += 256) {
        unsigned c = lh[0][i] + lh[1][i] + lh[2][i] + lh[3][i];
        if (c) atomicAdd(&gh[i], c);
    }
}

__global__ __launch_bounds__(256) void k_histB(const float* __restrict__ unc,
    const unsigned* __restrict__ meta, unsigned* __restrict__ hist)
{
    __shared__ unsigned lh[4096];
    int b = blockIdx.y, t = threadIdx.x;
    unsigned binA = meta[b * 8 + 0];
    for (int i = t; i < 4096; i += 256) lh[i] = 0;
    __syncthreads();
    const float4* src = (const float4*)(unc + (size_t)b * HW_IMG + blockIdx.x * 4096);
#pragma unroll
    for (int j = 0; j < 4; j++) {
        float4 v = src[j * 256 + t];
        unsigned k;
        k = f2key(v.x); if ((k >> 20) == binA) atomicAdd(&lh[(k >> 8) & 0xFFFu], 1u);
        k = f2key(v.y); if ((k >> 20) == binA) atomicAdd(&lh[(k >> 8) & 0xFFFu], 1u);
        k = f2key(v.z); if ((k >> 20) == binA) atomicAdd(&lh[(k >> 8) & 0xFFFu], 1u);
        k = f2key(v.w); if ((k >> 20) == binA) atomicAdd(&lh[(k >> 8) & 0xFFFu], 1u);
    }
    __syncthreads();
    unsigned* gh = hist + (size_t)b * 4096;
    for (int i = t; i < 4096; i += 256) { unsigned c = lh[i]; if (c) atomicAdd(&gh[i], c); }
}

__global__ __launch_bounds__(256) void k_histC(const float* __restrict__ unc,
    const unsigned* __restrict__ meta, unsigned* __restrict__ hist)
{
    __shared__ unsigned lh[256];
    int b = blockIdx.y, t = threadIdx.x;
    unsigned pre24 = (meta[b * 8 + 0] << 12) | meta[b * 8 + 2];
    lh[t] = 0;
    __syncthreads();
    const float4* src = (const float4*)(unc + (size_t)b * HW_IMG + blockIdx.x * 4096);
#pragma unroll
    for (int j = 0; j < 4; j++) {
        float4 v = src[j * 256 + t];
        unsigned k;
        k = f2key(v.x); if ((k >> 8) == pre24) atomicAdd(&lh[k & 0xFFu], 1u);
        k = f2key(v.y); if ((k >> 8) == pre24) atomicAdd(&lh[k & 0xFFu], 1u);
        k = f2key(v.z); if ((k >> 8) == pre24) atomicAdd(&lh[k & 0xFFu], 1u);
        k = f2key(v.w); if ((k >> 8) == pre24) atomicAdd(&lh[k & 0xFFu], 1u);
    }
    __syncthreads();
    unsigned* gh = hist + (size_t)b * 4096;
    unsigned c = lh[t];
    if (c) atomicAdd(&gh[t], c);
}

__global__ __launch_bounds__(256) void k_find(const unsigned* __restrict__ hist,
    unsigned* __restrict__ meta, int per, int stage)
{
    int b = blockIdx.x, t = threadIdx.x;
    const unsigned* h = hist + (size_t)b * 4096;
    unsigned base = (stage == 0) ? 0u : meta[b * 8 + 2 * stage - 1];
    __shared__ unsigned seg[256], pref[256];
    unsigned s = 0;
    for (int i = 0; i < per; i++) s += h[t * per + i];
    seg[t] = s;
    __syncthreads();
    if (t == 0) { unsigned c = base; for (int i = 0; i < 256; i++) { pref[i] = c; c += seg[i]; } }
    __syncthreads();
    if (pref[t] < KSEL && KSEL <= pref[t] + seg[t]) {
        unsigned c = pref[t];
        for (int i = 0; i < per; i++) {
            unsigned cnt = h[t * per + i];
            if (c + cnt >= KSEL) {
                unsigned bin = (unsigned)(t * per + i);
                meta[b * 8 + 2 * stage] = bin;
                meta[b * 8 + 2 * stage + 1] = c;
                if (stage == 2)
                    meta[b * 8 + 6] = (meta[b * 8 + 0] << 20) | (meta[b * 8 + 2] << 8) | bin;
                break;
            }
            c += cnt;
        }
    }
}

__global__ __launch_bounds__(256) void k_count(const float* __restrict__ unc,
    const unsigned* __restrict__ meta, unsigned* __restrict__ cntL, unsigned* __restrict__ cntE)
{
    int b = blockIdx.y, blk = blockIdx.x, t = threadIdx.x;
    unsigned pivot = meta[b * 8 + 6];
    const float4* src = (const float4*)(unc + (size_t)b * HW_IMG + blk * 1024);
    float4 v = src[t];
    unsigned k0 = f2key(v.x), k1 = f2key(v.y), k2 = f2key(v.z), k3 = f2key(v.w);
    unsigned cl = (k0 < pivot) + (k1 < pivot) + (k2 < pivot) + (k3 < pivot);
    unsigned ce = (k0 == pivot) + (k1 == pivot) + (k2 == pivot) + (k3 == pivot);
    __shared__ unsigned rl[256], re[256];
    rl[t] = cl; re[t] = ce; __syncthreads();
    for (int s = 128; s > 0; s >>= 1) { if (t < s) { rl[t] += rl[t + s]; re[t] += re[t + s]; } __syncthreads(); }
    if (t == 0) { cntL[b * 256 + blk] = rl[0]; cntE[b * 256 + blk] = re[0]; }
}

__global__ void k_scan(const unsigned* __restrict__ cntL, const unsigned* __restrict__ cntE,
                       unsigned* __restrict__ offL, unsigned* __restrict__ offE)
{
    int b = blockIdx.x;
    if (threadIdx.x == 0) {
        unsigned c = 0;
        for (int i = 0; i < 256; i++) { offL[b * 256 + i] = c; c += cntL[b * 256 + i]; }
        c = 0;
        for (int i = 0; i < 256; i++) { offE[b * 256 + i] = c; c += cntE[b * 256 + i]; }
    }
}

__global__ __launch_bounds__(256) void k_emit(const float* __restrict__ unc,
    const unsigned* __restrict__ meta, const unsigned* __restrict__ offL,
    const unsigned* __restrict__ offE, unsigned* __restrict__ sel)
{
    int b = blockIdx.y, blk = blockIdx.x, t = threadIdx.x;
    unsigned pivot = meta[b * 8 + 6], cless = meta[b * 8 + 5], r = KSEL - cless;
    int base = blk * 1024 + t * 4;
    const float4* src = (const float4*)(unc + (size_t)b * HW_IMG + blk * 1024);
    float4 v = src[t];
    unsigned key[4] = { f2key(v.x), f2key(v.y), f2key(v.z), f2key(v.w) };
    unsigned cl = 0, ce = 0;
#pragma unroll
    for (int j = 0; j < 4; j++) { cl += (key[j] < pivot); ce += (key[j] == pivot); }
    __shared__ unsigned sL[256], sE[256];
    sL[t] = cl; sE[t] = ce; __syncthreads();
    for (int off = 1; off < 256; off <<= 1) {
        unsigned aL = (t >= off) ? sL[t - off] : 0u;
        unsigned aE = (t >= off) ? sE[t - off] : 0u;
        __syncthreads();
        sL[t] += aL; sE[t] += aE;
        __syncthreads();
    }
    unsigned posL = offL[b * 256 + blk] + sL[t] - cl;
    unsigned posE = offE[b * 256 + blk] + sE[t] - ce;
    unsigned* sb = sel + (size_t)b * KSEL;
#pragma unroll
    for (int j = 0; j < 4; j++) {
        if (key[j] < pivot) { sb[posL++] = (unsigned)(base + j); }
        else if (key[j] == pivot) { if (posE < r) sb[cless + posE] = (unsigned)(base + j); posE++; }
    }
}

// ---------------- decoupled gather: bilinear taps -> gout [B][NPTS_PAD][256] bf16 ----------------
// channel interleave sub*8 + ch*32: each 4-lane point-group's store covers a
// contiguous 64B sector (write-amplification fix, verified round 5: 481->~115MB)
__global__ __launch_bounds__(256) void k_gather(
    const unsigned* __restrict__ sel, const unsigned short* __restrict__ encT,
    unsigned short* __restrict__ gout)
{
    // XCD pinning: blocks with wg%8==b land on XCD b; batch b's encT slice stays L2-hot
    int wg = blockIdx.x;
    int b  = wg & 7;
    int pbase = (wg >> 3) * 64;
    int t = threadIdx.x;
    const unsigned* selb = sel + (size_t)b * KSEL;

    int wv2 = t >> 6, l2 = t & 63;
    int g = l2 >> 2, sub = l2 & 3;
    int p = wv2 * 16 + g;
    int gi = pbase + p; if (gi >= KSEL) gi = KSEL - 1;
    unsigned id = selb[gi];
    int col = id & 511, row = (int)(id >> 9);
    float xf = (col - 1.5f) * 0.25f;
    float yf = (row - 1.5f) * 0.25f;
    float x0f = floorf(xf), y0f = floorf(yf);
    int x0 = (int)x0f, y0 = (int)y0f;
    float wx = xf - x0f, wy = yf - y0f;
    float wxa = (x0 >= 0) ? (1.f - wx) : 0.f;
    float wxb = (x0 <= 126) ? wx : 0.f;
    float wya = (y0 >= 0) ? (1.f - wy) : 0.f;
    float wyb = (y0 <= 126) ? wy : 0.f;
    int xc0 = x0 < 0 ? 0 : x0;
    int xc1 = (x0 + 1 > 127) ? 127 : x0 + 1;
    int yc0 = y0 < 0 ? 0 : y0;
    int yc1 = (y0 + 1 > 127) ? 127 : y0 + 1;
    float w00 = wxa * wya, w10 = wxb * wya, w01 = wxa * wyb, w11 = wxb * wyb;
    const unsigned short* bb = encT + (size_t)b * 16384 * CF;
    const unsigned short* p00 = bb + (size_t)(yc0 * 128 + xc0) * CF + sub * 8;
    const unsigned short* p10 = bb + (size_t)(yc0 * 128 + xc1) * CF + sub * 8;
    const unsigned short* p01 = bb + (size_t)(yc1 * 128 + xc0) * CF + sub * 8;
    const unsigned short* p11 = bb + (size_t)(yc1 * 128 + xc1) * CF + sub * 8;
    unsigned short* dst = gout + ((size_t)b * NPTS_PAD + pbase + p) * CF + sub * 8;
#pragma unroll 4
    for (int ch = 0; ch < 8; ch++) {
        int off = ch * 32;
        short8 va = *(const short8*)(p00 + off);
        short8 vb = *(const short8*)(p10 + off);
        short8 vc = *(const short8*)(p01 + off);
        short8 vd = *(const short8*)(p11 + off);
        short8 rr;
#pragma unroll
        for (int j = 0; j < 8; j++) {
            float f = w00 * bf2f((unsigned short)va[j]) + w10 * bf2f((unsigned short)vb[j])
                    + w01 * bf2f((unsigned short)vc[j]) + w11 * bf2f((unsigned short)vd[j]);
            rr[j] = (short)f2bf(f);
        }
        *(short8*)(dst + off) = rr;
    }
}

// ---------------- MLP + scatter: 128 pts/block, 8 waves, wave = 2 m-tiles x 8 n-tiles ----
// All 8 waves cover the 256 output channels exactly once -> weights read once per
// block (halves weight L2 traffic vs 64-pt blocks), 2 global weight loads per K-step.
__global__ __launch_bounds__(512, 4) void k_mlp(
    const unsigned* __restrict__ sel, const float* __restrict__ prev,
    const unsigned short* __restrict__ gout,
    const unsigned short* __restrict__ w1p, const unsigned short* __restrict__ w2p,
    const float* __restrict__ c1, const float* __restrict__ c2,
    const float* __restrict__ w3, const float* __restrict__ b3,
    float* __restrict__ out)
{
    __shared__ __align__(16) unsigned short act[128][LDACT];  // 75.8 KB
    __shared__ float sPart[8][128];

    int wg = blockIdx.x;
    int b  = wg & 7;                  // XCD pinning
    int pbase = (wg >> 3) * 128;
    int npts = KSEL - pbase; if (npts > 128) npts = 128;
    int t = threadIdx.x;
    const unsigned* selb = sel + (size_t)b * KSEL;

    // stage gathered tile: linear coalesced global read -> swizzled LDS write
    const unsigned short* src = gout + ((size_t)b * NPTS_PAD + pbase) * CF;
#pragma unroll
    for (int i = 0; i < 8; i++) {
        int e = i * 4096 + t * 8;           // e < 32768
        short8 v = *(const short8*)(src + e);
        int pp = e >> 8, c = e & 255;
        *(short8*)&act[pp][ACOL(c)] = v;
    }
    // coarse feature + zero K-padding (cols 256..287, ACOL identity there)
    if (t < 128) {
        int gi = pbase + t; if (gi >= KSEL) gi = KSEL - 1;
        unsigned id = selb[gi];
        float cv = prev[(size_t)b * HW_IMG + id];
        short8 z = {0,0,0,0,0,0,0,0};
        short8 c8 = z; c8[0] = (short)f2bf(cv);
        *(short8*)&act[t][256] = c8;
        *(short8*)&act[t][264] = z;
        *(short8*)&act[t][272] = z;
        *(short8*)&act[t][280] = z;
    }
    __syncthreads();

    int w = t >> 6, l = t & 63;       // wave 0..7
    int lr = l & 15, lk = l >> 4;
    f32x4 acc[2][8];
#pragma unroll
    for (int m = 0; m < 2; m++)
#pragma unroll
        for (int n = 0; n < 8; n++) acc[m][n] = (f32x4){0.f, 0.f, 0.f, 0.f};

    // layer 1: 256 x 288 (K padded); wave w owns ch rows w*32 .. w*32+31
#pragma unroll
    for (int kk = 0; kk < 9; kk++) {
        int k0 = kk * 32 + lk * 8;
        int k0s = ACOL(k0);
        short8 afr[2], bfr[8];
#pragma unroll
        for (int m = 0; m < 2; m++)
            afr[m] = *(const short8*)(w1p + (size_t)(w * 32 + m * 16 + lr) * LDW1 + k0);
#pragma unroll
        for (int n = 0; n < 8; n++)
            bfr[n] = *(const short8*)&act[n * 16 + lr][k0s];
#pragma unroll
        for (int m = 0; m < 2; m++)
#pragma unroll
            for (int n = 0; n < 8; n++)
                acc[m][n] = __builtin_amdgcn_mfma_f32_16x16x32_bf16(afr[m], bfr[n], acc[m][n], 0, 0, 0);
    }
    __syncthreads();   // everyone done reading act before overwrite

    // epilogue L1: bias + relu + bf16, write transposed into act (cols 0..255)
#pragma unroll
    for (int m = 0; m < 2; m++) {
        int chb = w * 32 + m * 16 + lk * 4;
        int chbs = ACOL(chb);
        float c0 = c1[chb], cA = c1[chb + 1], cB = c1[chb + 2], cC = c1[chb + 3];
#pragma unroll
        for (int n = 0; n < 8; n++) {
            int p = n * 16 + lr;
            float v0 = fmaxf(acc[m][n][0] + c0, 0.f);
            float v1 = fmaxf(acc[m][n][1] + cA, 0.f);
            float v2 = fmaxf(acc[m][n][2] + cB, 0.f);
            float v3 = fmaxf(acc[m][n][3] + cC, 0.f);
            u32x2 pk;
            pk[0] = (unsigned)f2bf(v0) | ((unsigned)f2bf(v1) << 16);
            pk[1] = (unsigned)f2bf(v2) | ((unsigned)f2bf(v3) << 16);
            *(u32x2*)&act[p][chbs] = pk;
        }
    }
    __syncthreads();

    // layer 2: 256 x 256
#pragma unroll
    for (int m = 0; m < 2; m++)
#pragma unroll
        for (int n = 0; n < 8; n++) acc[m][n] = (f32x4){0.f, 0.f, 0.f, 0.f};
#pragma unroll
    for (int kk = 0; kk < 8; kk++) {
        int k0 = kk * 32 + lk * 8;
        int k0s = ACOL(k0);
        short8 afr[2], bfr[8];
#pragma unroll
        for (int m = 0; m < 2; m++)
            afr[m] = *(const short8*)(w2p + (size_t)(w * 32 + m * 16 + lr) * 256 + k0);
#pragma unroll
        for (int n = 0; n < 8; n++)
            bfr[n] = *(const short8*)&act[n * 16 + lr][k0s];
#pragma unroll
        for (int m = 0; m < 2; m++)
#pragma unroll
            for (int n = 0; n < 8; n++)
                acc[m][n] = __builtin_amdgcn_mfma_f32_16x16x32_bf16(afr[m], bfr[n], acc[m][n], 0, 0, 0);
    }

    // layer 3: per-lane partial dot over this wave's 32 channels
    float part[8] = {0.f, 0.f, 0.f, 0.f, 0.f, 0.f, 0.f, 0.f};
#pragma unroll
    for (int m = 0; m < 2; m++) {
        int chb = w * 32 + m * 16 + lk * 4;
#pragma unroll
        for (int r = 0; r < 4; r++) {
            float wr = w3[chb + r];
            float cr = c2[chb + r];
#pragma unroll
            for (int n = 0; n < 8; n++)
                part[n] += wr * fmaxf(acc[m][n][r] + cr, 0.f);
        }
    }
#pragma unroll
    for (int n = 0; n < 8; n++) {
        part[n] += __shfl_xor(part[n], 16);
        part[n] += __shfl_xor(part[n], 32);
    }
    if (lk == 0) {
#pragma unroll
        for (int n = 0; n < 8; n++) sPart[w][n * 16 + lr] = part[n];
    }
    __syncthreads();
    if (t < 128 && t < npts) {
        float tot = b3[0];
#pragma unroll
        for (int ww = 0; ww < 8; ww++) tot += sPart[ww][t];
        float refined = 1.f / (1.f + __expf(-tot));
        unsigned id = selb[pbase + t];
        out[(size_t)b * HW_IMG + id] = refined;
    }
}

extern "C" void kernel_launch(void* const* d_in, const int* in_sizes, int n_in,
                              void* d_out, int out_size, void* d_ws, size_t ws_size,
                              hipStream_t stream)
{
    (void)in_sizes; (void)n_in; (void)out_size; (void)ws_size;
    const float* unc  = (const float*)d_in[0];
    const float* prev = (const float*)d_in[1];
    const float* enc  = (const float*)d_in[2];
    const float* w1   = (const float*)d_in[3];
    const float* b1   = (const float*)d_in[4];
    const float* g1   = (const float*)d_in[5];
    const float* be1  = (const float*)d_in[6];
    const float* m1   = (const float*)d_in[7];
    const float* v1   = (const float*)d_in[8];
    const float* w2   = (const float*)d_in[9];
    const float* b2   = (const float*)d_in[10];
    const float* g2   = (const float*)d_in[11];
    const float* be2  = (const float*)d_in[12];
    const float* m2   = (const float*)d_in[13];
    const float* v2   = (const float*)d_in[14];
    const float* w3   = (const float*)d_in[15];
    const float* b3   = (const float*)d_in[16];
    float* out = (float*)d_out;

    char* ws = (char*)d_ws;
    size_t off = 0;
    auto alloc = [&](size_t bytes) { size_t o = off; off += (bytes + 255) & ~(size_t)255; return o; };
    size_t o_encT = alloc((size_t)NB * 16384 * CF * 2);       // 67.1 MB
    size_t o_gout = alloc((size_t)NB * NPTS_PAD * CF * 2);    // 107.5 MB
    size_t o_w1p  = alloc((size_t)256 * LDW1 * 2);
    size_t o_w2p  = alloc((size_t)256 * 256 * 2);
    size_t o_c1   = alloc(256 * 4);
    size_t o_c2   = alloc(256 * 4);
    size_t o_hist = alloc((size_t)3 * NB * 4096 * 4);         // histA/B/C
    size_t o_meta = alloc(NB * 8 * 4);
    size_t o_cntL = alloc(NB * 256 * 4);
    size_t o_cntE = alloc(NB * 256 * 4);
    size_t o_offL = alloc(NB * 256 * 4);
    size_t o_offE = alloc(NB * 256 * 4);
    size_t o_sel  = alloc((size_t)NB * KSEL * 4);

    unsigned short* encT = (unsigned short*)(ws + o_encT);
    unsigned short* goutp= (unsigned short*)(ws + o_gout);
    unsigned short* w1p  = (unsigned short*)(ws + o_w1p);
    unsigned short* w2p  = (unsigned short*)(ws + o_w2p);
    float* c1p = (float*)(ws + o_c1);
    float* c2p = (float*)(ws + o_c2);
    unsigned* histA = (unsigned*)(ws + o_hist);
    unsigned* histB = histA + (size_t)NB * 4096;
    unsigned* histC = histB + (size_t)NB * 4096;
    unsigned* meta  = (unsigned*)(ws + o_meta);
    unsigned* cntL  = (unsigned*)(ws + o_cntL);
    unsigned* cntE  = (unsigned*)(ws + o_cntE);
    unsigned* offL  = (unsigned*)(ws + o_offL);
    unsigned* offE  = (unsigned*)(ws + o_offE);
    unsigned* sel   = (unsigned*)(ws + o_sel);

    hipMemsetAsync(ws + o_hist, 0, (size_t)3 * NB * 4096 * 4, stream);
    hipMemcpyAsync(d_out, (const void*)prev, (size_t)NB * HW_IMG * 4, hipMemcpyDeviceToDevice, stream);

    k_prep<<<544, 256, 0, stream>>>(w1, w2, b1, g1, be1, m1, v1, b2, g2, be2, m2, v2,
                                    w1p, w2p, c1p, c2p);
    k_transpose<<<dim3(256, 4, NB), 256, 0, stream>>>(enc, encT);

    k_histA<<<dim3(64, NB), 256, 0, stream>>>(unc, histA);
    k_find <<<NB, 256, 0, stream>>>(histA, meta, 16, 0);
    k_histB<<<dim3(64, NB), 256, 0, stream>>>(unc, meta, histB);
    k_find <<<NB, 256, 0, stream>>>(histB, meta, 16, 1);
    k_histC<<<dim3(64, NB), 256, 0, stream>>>(unc, meta, histC);
    k_find <<<NB, 256, 0, stream>>>(histC, meta, 1, 2);
    k_count<<<dim3(256, NB), 256, 0, stream>>>(unc, meta, cntL, cntE);
    k_scan <<<NB, 64, 0, stream>>>(cntL, cntE, offL, offE);
    k_emit <<<dim3(256, NB), 256, 0, stream>>>(unc, meta, offL, offE, sel);

    k_gather<<<GBLK * NB, 256, 0, stream>>>(sel, encT, goutp);
    k_mlp   <<<MBLK * NB, 512, 0, stream>>>(sel, prev, goutp, w1p, w2p,
                                            c1p, c2p, w3, b3, out);
}

// Round 7
// 218.644 us; speedup vs baseline: 2.0836x; 1.0714x over previous
//
#include <hip/hip_runtime.h>
#include <hip/hip_bf16.h>

#define HW_IMG 262144   // 512*512
#define KSEL   26214    // HW_IMG/10
#define NB     8
#define CF     256
#define LDACT  264      // LDS activation row stride (elements), K=256 + 8 pad
#define GBLK   410      // gather tiles (64 pts) per batch
#define MBLK   205      // mlp tiles (128 pts) per batch
#define NPTS_PAD 26240  // 410*64 = 205*128

// column swizzle for act: XOR element-index bits 4-5 with bits 6-7.
// stage writes conflict-free, MFMA B-reads 2-way, epilogue 2-way. Bijective on [0,256).
#define ACOL(c) ((c) ^ ((((c) >> 6) & 3) << 4))

typedef short    short8 __attribute__((ext_vector_type(8)));
typedef float    f32x4  __attribute__((ext_vector_type(4)));
typedef unsigned u32x2  __attribute__((ext_vector_type(2)));
typedef unsigned short u16x4 __attribute__((ext_vector_type(4)));

__device__ __forceinline__ unsigned f2key(float f){
    unsigned u = __builtin_bit_cast(unsigned, f);
    return (u & 0x80000000u) ? ~u : (u | 0x80000000u);
}
__device__ __forceinline__ unsigned short f2bf(float f){
    unsigned u = __builtin_bit_cast(unsigned, f);
    u = u + 0x7FFFu + ((u >> 16) & 1u);
    return (unsigned short)(u >> 16);
}
__device__ __forceinline__ float bf2f(unsigned short s){
    unsigned u = ((unsigned)s) << 16;
    return __builtin_bit_cast(float, u);
}

// ---------------- weight prep: fold BN, convert to bf16 ----------------
// w1p: [256][256] fine-channel weights (col k <- w1 col k+1); w1c0: coarse weight (f32)
__global__ __launch_bounds__(256) void k_prep(
    const float* __restrict__ w1, const float* __restrict__ w2,
    const float* __restrict__ b1, const float* __restrict__ g1, const float* __restrict__ be1,
    const float* __restrict__ m1, const float* __restrict__ v1,
    const float* __restrict__ b2, const float* __restrict__ g2, const float* __restrict__ be2,
    const float* __restrict__ m2, const float* __restrict__ v2,
    unsigned short* __restrict__ w1p, unsigned short* __restrict__ w2p,
    float* __restrict__ c1, float* __restrict__ c2, float* __restrict__ w1c0)
{
    int tid = blockIdx.x * 256 + threadIdx.x;
    if (tid < 65536) {
        int o = tid >> 8, k = tid & 255;
        float scale = g1[o] * rsqrtf(v1[o] + 1e-5f);
        w1p[tid] = f2bf(w1[o * 257 + k + 1] * scale);
        if (k == 0) {
            c1[o] = (b1[o] - m1[o]) * scale + be1[o];
            w1c0[o] = w1[o * 257] * scale;
        }
    } else {
        int t2 = tid - 65536;
        int o = t2 >> 8;
        float scale = g2[o] * rsqrtf(v2[o] + 1e-5f);
        w2p[t2] = f2bf(w2[t2] * scale);
        if ((t2 & 255) == 0) c2[o] = (b2[o] - m2[o]) * scale + be2[o];
    }
}

// ---------------- enc_f transpose: [B,C,128,128] f32 -> [B,pix,C] bf16 ----------------
// batch->XCD pinned (b = wg&7); enc reads nontemporal (streamed once)
__global__ __launch_bounds__(256) void k_transpose(
    const float* __restrict__ enc, unsigned short* __restrict__ encT)
{
    __shared__ __align__(16) unsigned short tile[64][72];
    int wg = blockIdx.x;
    int b = wg & 7;
    int r = wg >> 3;                 // 0..1023
    int pixbase = (r & 255) * 64;
    int chbase  = (r >> 8) * 64;
    int t = threadIdx.x;
    int pix = t & 63, cg = t >> 6;
    const float* src = enc + (size_t)b * CF * 16384;
#pragma unroll
    for (int i = 0; i < 16; i++) {
        int c = chbase + cg * 16 + i;
        float v = __builtin_nontemporal_load(&src[(size_t)c * 16384 + pixbase + pix]);
        tile[pix][cg * 16 + i] = f2bf(v);
    }
    __syncthreads();
    unsigned short* dst = encT + (size_t)b * 16384 * CF;
#pragma unroll
    for (int pass = 0; pass < 4; pass++) {
        int pl = pass * 16 + (t >> 4);
        int c4 = (t & 15) * 4;
        *(u16x4*)(dst + (size_t)(pixbase + pl) * CF + chbase + c4) = *(const u16x4*)&tile[pl][c4];
    }
}

// ---------------- selection: 12/12/8-bit radix select, LDS-privatized hists ----------------
// All selection kernels batch->XCD pinned: unc (1MB/batch) HBM-fetched once, L2-hit after.
// meta per batch: [0]=binA [1]=baseA [2]=binB [3]=baseB [4]=binC [5]=cless [6]=pivot

__global__ __launch_bounds__(256) void k_histA(const float* __restrict__ unc, unsigned* __restrict__ hist)
{
    __shared__ unsigned lh[4][4096];   // per-wave private copies (64 KB)
    int wg = blockIdx.x;
    int b = wg & 7, x = wg >> 3, t = threadIdx.x;
    int wv = t >> 6;
    for (int i = t; i < 4 * 4096; i += 256) ((unsigned*)lh)[i] = 0;
    __syncthreads();
    const float4* src = (const float4*)(unc + (size_t)b * HW_IMG + x * 4096);
    unsigned* mine = lh[wv];
#pragma unroll
    for (int j = 0; j < 4; j++) {
        float4 v = src[j * 256 + t];
        atomicAdd(&mine[f2key(v.x) >> 20], 1u);
        atomicAdd(&mine[f2key(v.y) >> 20], 1u);
        atomicAdd(&mine[f2key(v.z) >> 20], 1u);
        atomicAdd(&mine[f2key(v.w) >> 20], 1u);
    }
    __syncthreads();
    unsigned* gh = hist + (size_t)b * 4096;
    for (int i = t; i < 4096; i += 256) {
        unsigned c = lh[0][i] + lh[1][i] + lh[2][i] + lh[3][i];
        if (c) atomicAdd(&gh[i], c);
    }
}

__global__ __launch_bounds__(256) void k_histB(const float* __restrict__ unc,
    const unsigned* __restrict__ meta, unsigned* __restrict__ hist)
{
    __shared__ unsigned lh[4096];
    int wg = blockIdx.x;
    int b = wg & 7, x = wg >> 3, t = threadIdx.x;
    unsigned binA = meta[b * 8 + 0];
    for (int i = t; i < 4096; i += 256) lh[i] = 0;
    __syncthreads();
    const float4* src = (const float4*)(unc + (size_t)b * HW_IMG + x * 4096);
#pragma unroll
    for (int j = 0; j < 4; j++) {
        float4 v = src[j * 256 + t];
        unsigned k;
        k = f2key(v.x); if ((k >> 20) == binA) atomicAdd(&lh[(k >> 8) & 0xFFFu], 1u);
        k = f2key(v.y); if ((k >> 20) == binA) atomicAdd(&lh[(k >> 8) & 0xFFFu], 1u);
        k = f2key(v.z); if ((k >> 20) == binA) atomicAdd(&lh[(k >> 8) & 0xFFFu], 1u);
        k = f2key(v.w); if ((k >> 20) == binA) atomicAdd(&lh[(k >> 8) & 0xFFFu], 1u);
    }
    __syncthreads();
    unsigned* gh = hist + (size_t)b * 4096;
    for (int i = t; i < 4096; i += 256) { unsigned c = lh[i]; if (c) atomicAdd(&gh[i], c); }
}

__global__ __launch_bounds__(256) void k_histC(const float* __restrict__ unc,
    const unsigned* __restrict__ meta, unsigned* __restrict__ hist)
{
    __shared__ unsigned lh[256];
    int wg = blockIdx.x;
    int b = wg & 7, x = wg >> 3, t = threadIdx.x;
    unsigned pre24 = (meta[b * 8 + 0] << 12) | meta[b * 8 + 2];
    lh[t] = 0;
    __syncthreads();
    const float4* src = (const float4*)(unc + (size_t)b * HW_IMG + x * 4096);
#pragma unroll
    for (int j = 0; j < 4; j++) {
        float4 v = src[j * 256 + t];
        unsigned k;
        k = f2key(v.x); if ((k >> 8) == pre24) atomicAdd(&lh[k & 0xFFu], 1u);
        k = f2key(v.y); if ((k >> 8) == pre24) atomicAdd(&lh[k & 0xFFu], 1u);
        k = f2key(v.z); if ((k >> 8) == pre24) atomicAdd(&lh[k & 0xFFu], 1u);
        k = f2key(v.w); if ((k >> 8) == pre24) atomicAdd(&lh[k & 0xFFu], 1u);
    }
    __syncthreads();
    unsigned* gh = hist + (size_t)b * 4096;
    unsigned c = lh[t];
    if (c) atomicAdd(&gh[t], c);
}

__global__ __launch_bounds__(256) void k_find(const unsigned* __restrict__ hist,
    unsigned* __restrict__ meta, int per, int stage)
{
    int b = blockIdx.x, t = threadIdx.x;
    const unsigned* h = hist + (size_t)b * 4096;
    unsigned base = (stage == 0) ? 0u : meta[b * 8 + 2 * stage - 1];
    __shared__ unsigned seg[256], pref[256];
    unsigned s = 0;
    for (int i = 0; i < per; i++) s += h[t * per + i];
    seg[t] = s;
    __syncthreads();
    if (t == 0) { unsigned c = base; for (int i = 0; i < 256; i++) { pref[i] = c; c += seg[i]; } }
    __syncthreads();
    if (pref[t] < KSEL && KSEL <= pref[t] + seg[t]) {
        unsigned c = pref[t];
        for (int i = 0; i < per; i++) {
            unsigned cnt = h[t * per + i];
            if (c + cnt >= KSEL) {
                unsigned bin = (unsigned)(t * per + i);
                meta[b * 8 + 2 * stage] = bin;
                meta[b * 8 + 2 * stage + 1] = c;
                if (stage == 2)
                    meta[b * 8 + 6] = (meta[b * 8 + 0] << 20) | (meta[b * 8 + 2] << 8) | bin;
                break;
            }
            c += cnt;
        }
    }
}

__global__ __launch_bounds__(256) void k_count(const float* __restrict__ unc,
    const unsigned* __restrict__ meta, unsigned* __restrict__ cntL, unsigned* __restrict__ cntE)
{
    int wg = blockIdx.x;
    int b = wg & 7, blk = wg >> 3, t = threadIdx.x;
    unsigned pivot = meta[b * 8 + 6];
    const float4* src = (const float4*)(unc + (size_t)b * HW_IMG + blk * 1024);
    float4 v = src[t];
    unsigned k0 = f2key(v.x), k1 = f2key(v.y), k2 = f2key(v.z), k3 = f2key(v.w);
    unsigned cl = (k0 < pivot) + (k1 < pivot) + (k2 < pivot) + (k3 < pivot);
    unsigned ce = (k0 == pivot) + (k1 == pivot) + (k2 == pivot) + (k3 == pivot);
    __shared__ unsigned rl[256], re[256];
    rl[t] = cl; re[t] = ce; __syncthreads();
    for (int s = 128; s > 0; s >>= 1) { if (t < s) { rl[t] += rl[t + s]; re[t] += re[t + s]; } __syncthreads(); }
    if (t == 0) { cntL[b * 256 + blk] = rl[0]; cntE[b * 256 + blk] = re[0]; }
}

__global__ void k_scan(const unsigned* __restrict__ cntL, const unsigned* __restrict__ cntE,
                       unsigned* __restrict__ offL, unsigned* __restrict__ offE)
{
    int b = blockIdx.x;
    if (threadIdx.x == 0) {
        unsigned c = 0;
        for (int i = 0; i < 256; i++) { offL[b * 256 + i] = c; c += cntL[b * 256 + i]; }
        c = 0;
        for (int i = 0; i < 256; i++) { offE[b * 256 + i] = c; c += cntE[b * 256 + i]; }
    }
}

__global__ __launch_bounds__(256) void k_emit(const float* __restrict__ unc,
    const unsigned* __restrict__ meta, const unsigned* __restrict__ offL,
    const unsigned* __restrict__ offE, unsigned* __restrict__ sel)
{
    int wg = blockIdx.x;
    int b = wg & 7, blk = wg >> 3, t = threadIdx.x;
    unsigned pivot = meta[b * 8 + 6], cless = meta[b * 8 + 5], r = KSEL - cless;
    int base = blk * 1024 + t * 4;
    const float4* src = (const float4*)(unc + (size_t)b * HW_IMG + blk * 1024);
    float4 v = src[t];
    unsigned key[4] = { f2key(v.x), f2key(v.y), f2key(v.z), f2key(v.w) };
    unsigned cl = 0, ce = 0;
#pragma unroll
    for (int j = 0; j < 4; j++) { cl += (key[j] < pivot); ce += (key[j] == pivot); }
    __shared__ unsigned sL[256], sE[256];
    sL[t] = cl; sE[t] = ce; __syncthreads();
    for (int off = 1; off < 256; off <<= 1) {
        unsigned aL = (t >= off) ? sL[t - off] : 0u;
        unsigned aE = (t >= off) ? sE[t - off] : 0u;
        __syncthreads();
        sL[t] += aL; sE[t] += aE;
        __syncthreads();
    }
    unsigned posL = offL[b * 256 + blk] + sL[t] - cl;
    unsigned posE = offE[b * 256 + blk] + sE[t] - ce;
    unsigned* sb = sel + (size_t)b * KSEL;
#pragma unroll
    for (int j = 0; j < 4; j++) {
        if (key[j] < pivot) { sb[posL++] = (unsigned)(base + j); }
        else if (key[j] == pivot) { if (posE < r) sb[cless + posE] = (unsigned)(base + j); posE++; }
    }
}

// ---------------- decoupled gather: bilinear taps -> gout [B][NPTS_PAD][256] bf16 ----------------
// channel interleave sub*8 + ch*32 (full 64B sectors per 4-lane group, verified r5).
// gout stores NONTEMPORAL: keeps per-XCD L2 reserved for encT/weights.
__global__ __launch_bounds__(256) void k_gather(
    const unsigned* __restrict__ sel, const unsigned short* __restrict__ encT,
    unsigned short* __restrict__ gout)
{
    int wg = blockIdx.x;
    int b  = wg & 7;                 // XCD pinning
    int pbase = (wg >> 3) * 64;
    int t = threadIdx.x;
    const unsigned* selb = sel + (size_t)b * KSEL;

    int wv2 = t >> 6, l2 = t & 63;
    int g = l2 >> 2, sub = l2 & 3;
    int p = wv2 * 16 + g;
    int gi = pbase + p; if (gi >= KSEL) gi = KSEL - 1;
    unsigned id = selb[gi];
    int col = id & 511, row = (int)(id >> 9);
    float xf = (col - 1.5f) * 0.25f;
    float yf = (row - 1.5f) * 0.25f;
    float x0f = floorf(xf), y0f = floorf(yf);
    int x0 = (int)x0f, y0 = (int)y0f;
    float wx = xf - x0f, wy = yf - y0f;
    float wxa = (x0 >= 0) ? (1.f - wx) : 0.f;
    float wxb = (x0 <= 126) ? wx : 0.f;
    float wya = (y0 >= 0) ? (1.f - wy) : 0.f;
    float wyb = (y0 <= 126) ? wy : 0.f;
    int xc0 = x0 < 0 ? 0 : x0;
    int xc1 = (x0 + 1 > 127) ? 127 : x0 + 1;
    int yc0 = y0 < 0 ? 0 : y0;
    int yc1 = (y0 + 1 > 127) ? 127 : y0 + 1;
    float w00 = wxa * wya, w10 = wxb * wya, w01 = wxa * wyb, w11 = wxb * wyb;
    const unsigned short* bb = encT + (size_t)b * 16384 * CF;
    const unsigned short* p00 = bb + (size_t)(yc0 * 128 + xc0) * CF + sub * 8;
    const unsigned short* p10 = bb + (size_t)(yc0 * 128 + xc1) * CF + sub * 8;
    const unsigned short* p01 = bb + (size_t)(yc1 * 128 + xc0) * CF + sub * 8;
    const unsigned short* p11 = bb + (size_t)(yc1 * 128 + xc1) * CF + sub * 8;
    unsigned short* dst = gout + ((size_t)b * NPTS_PAD + pbase + p) * CF + sub * 8;
#pragma unroll 4
    for (int ch = 0; ch < 8; ch++) {
        int off = ch * 32;
        short8 va = *(const short8*)(p00 + off);
        short8 vb = *(const short8*)(p10 + off);
        short8 vc = *(const short8*)(p01 + off);
        short8 vd = *(const short8*)(p11 + off);
        short8 rr;
#pragma unroll
        for (int j = 0; j < 8; j++) {
            float f = w00 * bf2f((unsigned short)va[j]) + w10 * bf2f((unsigned short)vb[j])
                    + w01 * bf2f((unsigned short)vc[j]) + w11 * bf2f((unsigned short)vd[j]);
            rr[j] = (short)f2bf(f);
        }
        __builtin_nontemporal_store(rr, (short8*)(dst + off));
    }
}

// ---------------- MLP + scatter: 128 pts/block, 8 waves, wave = 2 m-tiles x 8 n-tiles ----
// L1 is K=256 MFMA + exact f32 rank-1 update for the coarse channel in the epilogue.
// gout/prev/out accesses NONTEMPORAL -> weights stay L2-resident (afr = L2 hit).
__global__ __launch_bounds__(512, 4) void k_mlp(
    const unsigned* __restrict__ sel, const float* __restrict__ prev,
    const unsigned short* __restrict__ gout,
    const unsigned short* __restrict__ w1p, const unsigned short* __restrict__ w2p,
    const float* __restrict__ c1, const float* __restrict__ c2,
    const float* __restrict__ w3, const float* __restrict__ b3,
    const float* __restrict__ w1c0, float* __restrict__ out)
{
    __shared__ __align__(16) unsigned short act[128][LDACT];  // 67.6 KB
    __shared__ float sPart[8][128];
    __shared__ float sCoarse[128];

    int wg = blockIdx.x;
    int b  = wg & 7;                  // XCD pinning
    int pbase = (wg >> 3) * 128;
    int npts = KSEL - pbase; if (npts > 128) npts = 128;
    int t = threadIdx.x;
    const unsigned* selb = sel + (size_t)b * KSEL;

    // stage gathered tile: NT global read -> swizzled LDS write
    const unsigned short* src = gout + ((size_t)b * NPTS_PAD + pbase) * CF;
#pragma unroll
    for (int i = 0; i < 8; i++) {
        int e = i * 4096 + t * 8;           // e < 32768
        short8 v = __builtin_nontemporal_load((const short8*)(src + e));
        int pp = e >> 8, c = e & 255;
        *(short8*)&act[pp][ACOL(c)] = v;
    }
    // coarse feature (f32, used in rank-1 epilogue update)
    if (t < 128) {
        int gi = pbase + t; if (gi >= KSEL) gi = KSEL - 1;
        unsigned id = selb[gi];
        sCoarse[t] = __builtin_nontemporal_load(&prev[(size_t)b * HW_IMG + id]);
    }
    __syncthreads();

    int w = t >> 6, l = t & 63;       // wave 0..7
    int lr = l & 15, lk = l >> 4;
    f32x4 acc[2][8];
#pragma unroll
    for (int m = 0; m < 2; m++)
#pragma unroll
        for (int n = 0; n < 8; n++) acc[m][n] = (f32x4){0.f, 0.f, 0.f, 0.f};

    // layer 1: 256 x 256; wave w owns ch rows w*32 .. w*32+31
#pragma unroll
    for (int kk = 0; kk < 8; kk++) {
        int k0 = kk * 32 + lk * 8;
        int k0s = ACOL(k0);
        short8 afr[2], bfr[8];
#pragma unroll
        for (int m = 0; m < 2; m++)
            afr[m] = *(const short8*)(w1p + (size_t)(w * 32 + m * 16 + lr) * 256 + k0);
#pragma unroll
        for (int n = 0; n < 8; n++)
            bfr[n] = *(const short8*)&act[n * 16 + lr][k0s];
#pragma unroll
        for (int m = 0; m < 2; m++)
#pragma unroll
            for (int n = 0; n < 8; n++)
                acc[m][n] = __builtin_amdgcn_mfma_f32_16x16x32_bf16(afr[m], bfr[n], acc[m][n], 0, 0, 0);
    }
    __syncthreads();   // everyone done reading act before overwrite

    // epilogue L1: + coarse rank-1 + bias + relu + bf16, write transposed into act
#pragma unroll
    for (int m = 0; m < 2; m++) {
        int chb = w * 32 + m * 16 + lk * 4;
        int chbs = ACOL(chb);
        float c0 = c1[chb], cA = c1[chb + 1], cB = c1[chb + 2], cC = c1[chb + 3];
        float q0 = w1c0[chb], qA = w1c0[chb + 1], qB = w1c0[chb + 2], qC = w1c0[chb + 3];
#pragma unroll
        for (int n = 0; n < 8; n++) {
            int p = n * 16 + lr;
            float cv = sCoarse[p];
            float v0 = fmaxf(acc[m][n][0] + c0 + q0 * cv, 0.f);
            float v1 = fmaxf(acc[m][n][1] + cA + qA * cv, 0.f);
            float v2 = fmaxf(acc[m][n][2] + cB + qB * cv, 0.f);
            float v3 = fmaxf(acc[m][n][3] + cC + qC * cv, 0.f);
            u32x2 pk;
            pk[0] = (unsigned)f2bf(v0) | ((unsigned)f2bf(v1) << 16);
            pk[1] = (unsigned)f2bf(v2) | ((unsigned)f2bf(v3) << 16);
            *(u32x2*)&act[p][chbs] = pk;
        }
    }
    __syncthreads();

    // layer 2: 256 x 256
#pragma unroll
    for (int m = 0; m < 2; m++)
#pragma unroll
        for (int n = 0; n < 8; n++) acc[m][n] = (f32x4){0.f, 0.f, 0.f, 0.f};
#pragma unroll
    for (int kk = 0; kk < 8; kk++) {
        int k0 = kk * 32 + lk * 8;
        int k0s = ACOL(k0);
        short8 afr[2], bfr[8];
#pragma unroll
        for (int m = 0; m < 2; m++)
            afr[m] = *(const short8*)(w2p + (size_t)(w * 32 + m * 16 + lr) * 256 + k0);
#pragma unroll
        for (int n = 0; n < 8; n++)
            bfr[n] = *(const short8*)&act[n * 16 + lr][k0s];
#pragma unroll
        for (int m = 0; m < 2; m++)
#pragma unroll
            for (int n = 0; n < 8; n++)
                acc[m][n] = __builtin_amdgcn_mfma_f32_16x16x32_bf16(afr[m], bfr[n], acc[m][n], 0, 0, 0);
    }

    // layer 3: per-lane partial dot over this wave's 32 channels
    float part[8] = {0.f, 0.f, 0.f, 0.f, 0.f, 0.f, 0.f, 0.f};
#pragma unroll
    for (int m = 0; m < 2; m++) {
        int chb = w * 32 + m * 16 + lk * 4;
#pragma unroll
        for (int r = 0; r < 4; r++) {
            float wr = w3[chb + r];
            float cr = c2[chb + r];
#pragma unroll
            for (int n = 0; n < 8; n++)
                part[n] += wr * fmaxf(acc[m][n][r] + cr, 0.f);
        }
    }
#pragma unroll
    for (int n = 0; n < 8; n++) {
        part[n] += __shfl_xor(part[n], 16);
        part[n] += __shfl_xor(part[n], 32);
    }
    if (lk == 0) {
#pragma unroll
        for (int n = 0; n < 8; n++) sPart[w][n * 16 + lr] = part[n];
    }
    __syncthreads();
    if (t < 128 && t < npts) {
        float tot = b3[0];
#pragma unroll
        for (int ww = 0; ww < 8; ww++) tot += sPart[ww][t];
        float refined = 1.f / (1.f + __expf(-tot));
        unsigned id = selb[pbase + t];
        __builtin_nontemporal_store(refined, &out[(size_t)b * HW_IMG + id]);
    }
}

extern "C" void kernel_launch(void* const* d_in, const int* in_sizes, int n_in,
                              void* d_out, int out_size, void* d_ws, size_t ws_size,
                              hipStream_t stream)
{
    (void)in_sizes; (void)n_in; (void)out_size; (void)ws_size;
    const float* unc  = (const float*)d_in[0];
    const float* prev = (const float*)d_in[1];
    const float* enc  = (const float*)d_in[2];
    const float* w1   = (const float*)d_in[3];
    const float* b1   = (const float*)d_in[4];
    const float* g1   = (const float*)d_in[5];
    const float* be1  = (const float*)d_in[6];
    const float* m1   = (const float*)d_in[7];
    const float* v1   = (const float*)d_in[8];
    const float* w2   = (const float*)d_in[9];
    const float* b2   = (const float*)d_in[10];
    const float* g2   = (const float*)d_in[11];
    const float* be2  = (const float*)d_in[12];
    const float* m2   = (const float*)d_in[13];
    const float* v2   = (const float*)d_in[14];
    const float* w3   = (const float*)d_in[15];
    const float* b3   = (const float*)d_in[16];
    float* out = (float*)d_out;

    char* ws = (char*)d_ws;
    size_t off = 0;
    auto alloc = [&](size_t bytes) { size_t o = off; off += (bytes + 255) & ~(size_t)255; return o; };
    size_t o_encT = alloc((size_t)NB * 16384 * CF * 2);       // 67.1 MB
    size_t o_gout = alloc((size_t)NB * NPTS_PAD * CF * 2);    // 107.5 MB
    size_t o_w1p  = alloc((size_t)256 * 256 * 2);
    size_t o_w2p  = alloc((size_t)256 * 256 * 2);
    size_t o_c1   = alloc(256 * 4);
    size_t o_c2   = alloc(256 * 4);
    size_t o_w1c0 = alloc(256 * 4);
    size_t o_hist = alloc((size_t)3 * NB * 4096 * 4);         // histA/B/C
    size_t o_meta = alloc(NB * 8 * 4);
    size_t o_cntL = alloc(NB * 256 * 4);
    size_t o_cntE = alloc(NB * 256 * 4);
    size_t o_offL = alloc(NB * 256 * 4);
    size_t o_offE = alloc(NB * 256 * 4);
    size_t o_sel  = alloc((size_t)NB * KSEL * 4);

    unsigned short* encT = (unsigned short*)(ws + o_encT);
    unsigned short* goutp= (unsigned short*)(ws + o_gout);
    unsigned short* w1p  = (unsigned short*)(ws + o_w1p);
    unsigned short* w2p  = (unsigned short*)(ws + o_w2p);
    float* c1p = (float*)(ws + o_c1);
    float* c2p = (float*)(ws + o_c2);
    float* w1c0p = (float*)(ws + o_w1c0);
    unsigned* histA = (unsigned*)(ws + o_hist);
    unsigned* histB = histA + (size_t)NB * 4096;
    unsigned* histC = histB + (size_t)NB * 4096;
    unsigned* meta  = (unsigned*)(ws + o_meta);
    unsigned* cntL  = (unsigned*)(ws + o_cntL);
    unsigned* cntE  = (unsigned*)(ws + o_cntE);
    unsigned* offL  = (unsigned*)(ws + o_offL);
    unsigned* offE  = (unsigned*)(ws + o_offE);
    unsigned* sel   = (unsigned*)(ws + o_sel);

    hipMemsetAsync(ws + o_hist, 0, (size_t)3 * NB * 4096 * 4, stream);
    hipMemcpyAsync(d_out, (const void*)prev, (size_t)NB * HW_IMG * 4, hipMemcpyDeviceToDevice, stream);

    k_prep<<<512, 256, 0, stream>>>(w1, w2, b1, g1, be1, m1, v1, b2, g2, be2, m2, v2,
                                    w1p, w2p, c1p, c2p, w1c0p);
    k_transpose<<<8192, 256, 0, stream>>>(enc, encT);

    k_histA<<<512, 256, 0, stream>>>(unc, histA);
    k_find <<<NB, 256, 0, stream>>>(histA, meta, 16, 0);
    k_histB<<<512, 256, 0, stream>>>(unc, meta, histB);
    k_find <<<NB, 256, 0, stream>>>(histB, meta, 16, 1);
    k_histC<<<512, 256, 0, stream>>>(unc, meta, histC);
    k_find <<<NB, 256, 0, stream>>>(histC, meta, 1, 2);
    k_count<<<2048, 256, 0, stream>>>(unc, meta, cntL, cntE);
    k_scan <<<NB, 64, 0, stream>>>(cntL, cntE, offL, offE);
    k_emit <<<2048, 256, 0, stream>>>(unc, meta, offL, offE, sel);

    k_gather<<<GBLK * NB, 256, 0, stream>>>(sel, encT, goutp);
    k_mlp   <<<MBLK * NB, 512, 0, stream>>>(sel, prev, goutp, w1p, w2p,
                                            c1p, c2p, w3, b3, w1c0p, out);
}